// Round 10
// baseline (550.084 us; speedup 1.0000x reference)
//
#include <hip/hip_runtime.h>
#include <hip/hip_fp16.h>

#define TLEN 8192
#define NTS  256
#define CLEN 32
#define NCH  256           // TLEN / CLEN
#define SLOT2 66048        // 256*128 bf16 (65536) + 128 f32 scales (512)

typedef __bf16 bf16x8 __attribute__((ext_vector_type(8)));
typedef float  f32x4  __attribute__((ext_vector_type(4)));
union U128 { uint4 u; bf16x8 v; };
union U64  { uint2 u; long l; };

__device__ __forceinline__ unsigned f2bfu(float x) {
    unsigned u = __float_as_uint(x);
    return (u + 0x7fffu + ((u >> 16) & 1u)) >> 16;
}
__device__ __forceinline__ unsigned pk2(float lo, float hi) {
    return f2bfu(lo) | (f2bfu(hi) << 16);
}
__device__ __forceinline__ float bf2f(unsigned short h) {
    return __uint_as_float(((unsigned)h) << 16);
}
__device__ __forceinline__ unsigned pk4bf8(float a, float b, float c, float d) {
    int r = __builtin_amdgcn_cvt_pk_bf8_f32(a, b, 0, false);
    r = __builtin_amdgcn_cvt_pk_bf8_f32(c, d, r, true);
    return (unsigned)r;
}

// ===========================================================================
// Phase 1 (fp8): block = (chunk c, col-half h), 256 thr = 4 waves, wave owns
// 32 columns. Q in LDS as bf8 e5m2 (64 KiB) -> 2 blocks/CU. Output LINEAR:
// bf16 column-max-normalized matrix + f32 per-column log scales.
// Output coalesced via LDS transpose through qt8 (dead after last MFMA).
// ===========================================================================
__global__ __launch_bounds__(256, 2) void crf_phase1(
        const float* __restrict__ emit, const float* __restrict__ trans,
        char* __restrict__ outX) {
    __shared__ alignas(16) char qt8[65536];      // QT[j][k] bf8, granule-rotated
    __shared__ alignas(16) char scr[4][1280];    // exchange: 32 cols x 40 B/wave
    __shared__ alignas(16) float eld[2][NTS];    // exp(emit row), dbuf

    const int t    = threadIdx.x;
    const int lane = t & 63;
    const int w    = t >> 6;              // 0..3
    const int gl   = lane >> 4;           // 0..3
    const int ln15 = lane & 15;
    const int c    = blockIdx.x >> 1;
    const int h    = blockIdx.x & 1;
    const int istart = (c == 0) ? 1 : CLEN * c;
    const int iend   = CLEN * c + CLEN;

    // ---- stage QT[j][k] = exp(trans[k][j]) as bf8, rotated granules ------
    {
        const int ln = t & 15;
        for (int gk = 0; gk < 32; gk++) {
            float v[8];
            #pragma unroll
            for (int e = 0; e < 8; e++) v[e] = __expf(trans[(gk * 8 + e) * NTS + t]);
            uint2 u;
            u.x = pk4bf8(v[0], v[1], v[2], v[3]);
            u.y = pk4bf8(v[4], v[5], v[6], v[7]);
            const int p = (gk + 4 * ln + (ln >> 2)) & 31;
            *(uint2*)(qt8 + t * 256 + p * 8) = u;
        }
    }
    eld[istart & 1][t] = __expf(emit[istart * NTS + t]);

    int aoff[8];
    #pragma unroll
    for (int kf = 0; kf < 8; kf++) {
        const int p = (4 * kf + gl + 4 * ln15 + (ln15 >> 2)) & 31;
        aoff[kf] = ln15 * 256 + p * 8;
    }

    // ---- B := Identity columns (bf8 1.0 = 0x3C), rs := 0 -----------------
    uint2 Bf[8][2];
    #pragma unroll
    for (int kf = 0; kf < 8; kf++)
        #pragma unroll
        for (int cb = 0; cb < 2; cb++) {
            uint2 bu; bu.x = 0u; bu.y = 0u;
            const int r_glob = 128 * h + 32 * w + cb * 16 + ln15;
            if ((r_glob >> 3) == kf * 4 + gl) {
                const int e = r_glob & 7;
                if (e < 4) bu.x = 0x3Cu << (8 * e);
                else       bu.y = 0x3Cu << (8 * (e - 4));
            }
            Bf[kf][cb] = bu;
        }
    float rs[2] = {0.f, 0.f};
    __syncthreads();

    char* const mysc = &scr[w][0];
    for (int i = istart; i < iend; ++i) {
        float enext = 0.f;
        if (i + 1 < iend) enext = emit[(i + 1) * NTS + t];

        // ---- C = QT * B (bf8 MFMA) ---------------------------------------
        f32x4 Cacc[16][2];
        #pragma unroll
        for (int jb = 0; jb < 16; jb++)
            #pragma unroll
            for (int cb = 0; cb < 2; cb++) Cacc[jb][cb] = f32x4{0.f, 0.f, 0.f, 0.f};

        #pragma unroll
        for (int jb = 0; jb < 16; jb++) {
            #pragma unroll
            for (int kf = 0; kf < 8; kf++) {
                U64 a; a.u = *(const uint2*)(qt8 + (aoff[kf] + jb * 4096));
                #pragma unroll
                for (int cb = 0; cb < 2; cb++) {
                    U64 b; b.u = Bf[kf][cb];
                    Cacc[jb][cb] = __builtin_amdgcn_mfma_f32_16x16x32_bf8_bf8(
                        a.l, b.l, Cacc[jb][cb], 0, 0, 0);
                }
            }
        }

        // ---- scale rows j by exp(emit[i][j]) ------------------------------
        #pragma unroll
        for (int jb = 0; jb < 16; jb++) {
            float4 ev = *(const float4*)&eld[i & 1][jb * 16 + gl * 4];
            #pragma unroll
            for (int cb = 0; cb < 2; cb++) {
                Cacc[jb][cb][0] *= ev.x; Cacc[jb][cb][1] *= ev.y;
                Cacc[jb][cb][2] *= ev.z; Cacc[jb][cb][3] *= ev.w;
            }
        }
        // ---- per-column max + renormalize ---------------------------------
        float rn[2];
        #pragma unroll
        for (int cb = 0; cb < 2; cb++) {
            float m0 = Cacc[0][cb][0];
            #pragma unroll
            for (int jb = 0; jb < 16; jb++)
                #pragma unroll
                for (int rg = 0; rg < 4; rg++) m0 = fmaxf(m0, Cacc[jb][cb][rg]);
            m0 = fmaxf(m0, __shfl_xor(m0, 16));
            m0 = fmaxf(m0, __shfl_xor(m0, 32));
            rn[cb] = 1.0f / m0;
            rs[cb] += __logf(m0);
        }

        if (i == iend - 1) {
            // ---- coalesced write: scatter into qt8 (dead), then copy out ---
            __syncthreads();              // all waves done reading qt8 (MFMA)
            #pragma unroll
            for (int jb = 0; jb < 16; jb++)
                #pragma unroll
                for (int cb = 0; cb < 2; cb++) {
                    int rsl = w * 32 + cb * 16 + ln15;
                    #pragma unroll
                    for (int rg = 0; rg < 4; rg++) {
                        int j = jb * 16 + gl * 4 + rg;
                        *(unsigned short*)(qt8 + ((j * 128 + rsl) << 1)) =
                            (unsigned short)f2bfu(Cacc[jb][cb][rg] * rn[cb]);
                    }
                }
            __syncthreads();
            char* SO = outX + (size_t)(2 * c + h) * SLOT2;
            #pragma unroll
            for (int q = 0; q < 16; q++)
                *(uint4*)(SO + q * 4096 + t * 16) =
                    *(const uint4*)(qt8 + q * 4096 + t * 16);
            if (lane < 16) {
                #pragma unroll
                for (int cb = 0; cb < 2; cb++) {
                    int rsl = w * 32 + cb * 16 + lane;
                    *(float*)(SO + 65536 + rsl * 4) = rs[cb];
                }
            }
        } else {
            // ---- C -> next B (bf8) via intra-wave LDS exchange -------------
            #pragma unroll
            for (int kf = 0; kf < 8; kf++) {
                #pragma unroll
                for (int jbb = 0; jbb < 2; jbb++) {
                    const int jb = 2 * kf + jbb;
                    #pragma unroll
                    for (int cb = 0; cb < 2; cb++) {
                        const int col = cb * 16 + ln15;
                        unsigned pk = pk4bf8(Cacc[jb][cb][0] * rn[cb],
                                             Cacc[jb][cb][1] * rn[cb],
                                             Cacc[jb][cb][2] * rn[cb],
                                             Cacc[jb][cb][3] * rn[cb]);
                        *(unsigned*)(mysc + col * 40 + jbb * 16 + gl * 4) = pk;
                    }
                }
                asm volatile("s_waitcnt lgkmcnt(0)" ::: "memory");
                __builtin_amdgcn_sched_barrier(0);
                #pragma unroll
                for (int cb = 0; cb < 2; cb++) {
                    const int col = cb * 16 + ln15;
                    Bf[kf][cb] = *(const uint2*)(mysc + col * 40 + gl * 8);
                }
                asm volatile("s_waitcnt lgkmcnt(0)" ::: "memory");
                __builtin_amdgcn_sched_barrier(0);
            }
            eld[(i + 1) & 1][t] = __expf(enext);
            __syncthreads();
        }
    }
}

// ===========================================================================
// Fused run-of-8 combine: block (group g, half h) computes
// N_g = M_{8g+7} x ... x M_{8g+1} x M_{8g}, columns [128h,128h+128),
// via 7 serial staged matmuls (B kept in registers between stages).
// Grid 64 = 32 groups x 2 halves, ONE launch replaces 4 tree levels.
// ===========================================================================
__global__ __launch_bounds__(256, 1) void crf_combine_run(
        const char* __restrict__ inb, char* __restrict__ outb) {
    __shared__ alignas(16) char qt[131072];       // A staging, bf16 swizzled
    __shared__ alignas(16) unsigned scr[4][512];  // 2 KiB exchange per wave
    __shared__ alignas(16) float efac[NTS];
    __shared__ float smax[4];

    const int t = threadIdx.x;
    const int lane = t & 63;
    const int w = t >> 6;
    const int gl = lane >> 4;
    const int ln15 = lane & 15;
    const int g = blockIdx.x >> 1;
    const int h = blockIdx.x & 1;
    const char* SB = inb + (size_t)(16 * g + h) * SLOT2;   // M_{8g}, half h
    char* SO = outb + (size_t)(2 * g + h) * SLOT2;

    // ---- initial B frags from M_{8g} (raw bf16 bits) ---------------------
    bf16x8 Bf[8][2];
    #pragma unroll
    for (int kf = 0; kf < 8; kf++) {
        #pragma unroll
        for (int p2 = 0; p2 < 2; p2++) {
            int kk = p2 * 16 + (lane >> 2);
            uint4 d = *(const uint4*)(SB + (size_t)(32 * kf + kk) * 256
                                      + w * 64 + (lane & 3) * 16);
            *(uint4*)((char*)&scr[w][0] + kk * 64 + (lane & 3) * 16) = d;
        }
        asm volatile("s_waitcnt lgkmcnt(0)" ::: "memory");
        __builtin_amdgcn_sched_barrier(0);
        #pragma unroll
        for (int cb = 0; cb < 2; cb++) {
            unsigned wd[4] = {0u, 0u, 0u, 0u};
            #pragma unroll
            for (int e = 0; e < 8; e++) {
                int kloc = gl * 8 + e;
                unsigned short hh = *(const unsigned short*)
                    ((const char*)&scr[w][0] + kloc * 64 + (cb * 16 + ln15) * 2);
                wd[e >> 1] |= ((unsigned)hh) << (16 * (e & 1));
            }
            U128 q; q.u.x = wd[0]; q.u.y = wd[1]; q.u.z = wd[2]; q.u.w = wd[3];
            Bf[kf][cb] = q.v;
        }
        asm volatile("s_waitcnt lgkmcnt(0)" ::: "memory");
        __builtin_amdgcn_sched_barrier(0);
    }

    float logacc[2] = {0.f, 0.f};
    float rn[2];
    f32x4 Cacc[16][2];
    const int aswz = (lane & 7) << 4;

    for (int stg = 1; stg <= 7; ++stg) {
        const char* A0 = inb + (size_t)(16 * g + 2 * stg) * SLOT2;
        const char* A1 = A0 + SLOT2;

        // ---- sigma = max_k s_A[k]; efac[k] = exp(s_A[k] - sigma) ----------
        float sv = *(const float*)(((t < 128) ? A0 : A1) + 65536 + (t & 127) * 4);
        float m = sv;
        #pragma unroll
        for (int off = 32; off; off >>= 1) m = fmaxf(m, __shfl_xor(m, off));
        if (lane == 0) smax[w] = m;
        __syncthreads();                       // also fences prior qt reads
        const float sigma = fmaxf(fmaxf(smax[0], smax[1]),
                                  fmaxf(smax[2], smax[3]));
        efac[t] = __expf(sv - sigma);
        __syncthreads();

        // ---- stage A = S_A[j][k] * efac[k] into swizzled qt (bf16) --------
        for (int it = 0; it < 32; it++) {
            int off = it * 2048 + t * 8;
            int j = off >> 8, k = off & 255;
            const char* src = (k < 128) ? (A0 + (size_t)(j * 128 + k) * 2)
                                        : (A1 + (size_t)(j * 128 + (k - 128)) * 2);
            uint4 d = *(const uint4*)src;
            float4 e0 = *(const float4*)&efac[k];
            float4 e1 = *(const float4*)&efac[k + 4];
            float ef[8] = {e0.x, e0.y, e0.z, e0.w, e1.x, e1.y, e1.z, e1.w};
            unsigned wds[4] = {d.x, d.y, d.z, d.w};
            unsigned outw[4];
            #pragma unroll
            for (int wi = 0; wi < 4; wi++) {
                float lo = bf2f((unsigned short)(wds[wi] & 0xffffu)) * ef[2 * wi];
                float hi = bf2f((unsigned short)(wds[wi] >> 16)) * ef[2 * wi + 1];
                outw[wi] = pk2(lo, hi);
            }
            uint4 o; o.x = outw[0]; o.y = outw[1]; o.z = outw[2]; o.w = outw[3];
            *(uint4*)(qt + ((j * 512 + k * 2) ^ ((j & 7) << 4))) = o;
        }
        __syncthreads();

        // ---- C = A * B ----------------------------------------------------
        #pragma unroll
        for (int jb = 0; jb < 16; jb++)
            #pragma unroll
            for (int cb = 0; cb < 2; cb++) Cacc[jb][cb] = f32x4{0.f, 0.f, 0.f, 0.f};
        #pragma unroll
        for (int jb = 0; jb < 16; jb++) {
            const int abase = (jb * 16 + ln15) * 512 + gl * 16;
            #pragma unroll
            for (int kf = 0; kf < 8; kf++) {
                U128 a; a.u = *(const uint4*)(qt + ((abase + kf * 64) ^ aswz));
                #pragma unroll
                for (int cb = 0; cb < 2; cb++)
                    Cacc[jb][cb] = __builtin_amdgcn_mfma_f32_16x16x32_bf16(
                        a.v, Bf[kf][cb], Cacc[jb][cb], 0, 0, 0);
            }
        }

        // ---- per-column renorm; accumulate log scale ----------------------
        #pragma unroll
        for (int cb = 0; cb < 2; cb++) {
            float m0 = Cacc[0][cb][0];
            #pragma unroll
            for (int jb = 0; jb < 16; jb++)
                #pragma unroll
                for (int rg = 0; rg < 4; rg++) m0 = fmaxf(m0, Cacc[jb][cb][rg]);
            m0 = fmaxf(m0, __shfl_xor(m0, 16));
            m0 = fmaxf(m0, __shfl_xor(m0, 32));
            rn[cb] = 1.0f / m0;
            logacc[cb] += sigma + __logf(m0);
        }

        if (stg < 7) {
            // ---- Cacc -> Bf (bf16) via intra-wave exchange -----------------
            #pragma unroll
            for (int kf = 0; kf < 8; kf++) {
                #pragma unroll
                for (int jbb = 0; jbb < 2; jbb++) {
                    const int jb = 2 * kf + jbb;
                    const int koct = 2 * jbb + (gl >> 1);
                    #pragma unroll
                    for (int cb = 0; cb < 2; cb++) {
                        const int addr = (koct * 512 + (cb * 16 + ln15) * 16
                                          + (gl & 1) * 8) ^ (koct << 4);
                        uint2 pk;
                        pk.x = pk2(Cacc[jb][cb][0] * rn[cb], Cacc[jb][cb][1] * rn[cb]);
                        pk.y = pk2(Cacc[jb][cb][2] * rn[cb], Cacc[jb][cb][3] * rn[cb]);
                        *(uint2*)((char*)&scr[w][0] + addr) = pk;
                    }
                }
                asm volatile("s_waitcnt lgkmcnt(0)" ::: "memory");
                __builtin_amdgcn_sched_barrier(0);
                #pragma unroll
                for (int cb = 0; cb < 2; cb++) {
                    const int rb = (gl * 512 + (cb * 16 + ln15) * 16) ^ (gl << 4);
                    U128 q; q.u = *(const uint4*)((const char*)&scr[w][0] + rb);
                    Bf[kf][cb] = q.v;
                }
                asm volatile("s_waitcnt lgkmcnt(0)" ::: "memory");
                __builtin_amdgcn_sched_barrier(0);
            }
        }
    }

    // ---- coalesced write via qt reuse ------------------------------------
    __syncthreads();
    #pragma unroll
    for (int jb = 0; jb < 16; jb++)
        #pragma unroll
        for (int cb = 0; cb < 2; cb++) {
            int rsl = w * 32 + cb * 16 + ln15;
            #pragma unroll
            for (int rg = 0; rg < 4; rg++) {
                int j = jb * 16 + gl * 4 + rg;
                *(unsigned short*)(qt + ((j * 128 + rsl) << 1)) =
                    (unsigned short)f2bfu(Cacc[jb][cb][rg] * rn[cb]);
            }
        }
    __syncthreads();
    #pragma unroll
    for (int q = 0; q < 16; q++)
        *(uint4*)(SO + q * 4096 + t * 16) = *(const uint4*)(qt + q * 4096 + t * 16);
    if (lane < 16) {
        #pragma unroll
        for (int cb = 0; cb < 2; cb++) {
            int rsl = w * 32 + cb * 16 + lane;
            float sb = *(const float*)(SB + 65536 + rsl * 4);
            *(float*)(SO + 65536 + rsl * 4) = sb + logacc[cb];
        }
    }
}

// ===========================================================================
// Fused chain + finalize + gold: 32 remaining matrices applied as serial
// matvecs to alpha0; logZ = W + log(sum w); out = logZ - gold.
// ===========================================================================
__global__ __launch_bounds__(512) void crf_chainfin(
        const char* __restrict__ mats, const float* __restrict__ emit,
        const float* __restrict__ BOS, const int* __restrict__ y,
        const float* __restrict__ trans, const float* __restrict__ EOS,
        float* __restrict__ out) {
    __shared__ float red[8];
    __shared__ float smx[8];
    __shared__ alignas(16) float u[NTS];
    __shared__ float pu[NTS];
    const int t = threadIdx.x, lane = t & 63, wv = t >> 6;

    // ---- gold partial -----------------------------------------------------
    float s = 0.f;
    for (int i = t; i < TLEN - 1; i += 512) {
        int yi = y[i], yn = y[i + 1];
        s += trans[yi * NTS + yn] + emit[i * NTS + yi];
    }
    #pragma unroll
    for (int off = 32; off; off >>= 1) s += __shfl_down(s, off);
    if (lane == 0) red[wv] = s;

    // ---- init: w = exp(BOS + emit0 - m0) ---------------------------------
    float v0 = (t < NTS) ? (BOS[t] + emit[t]) : -INFINITY;
    float m = v0;
    #pragma unroll
    for (int off = 32; off; off >>= 1) m = fmaxf(m, __shfl_xor(m, off));
    if (lane == 0) smx[wv] = m;
    __syncthreads();
    const float m0 = fmaxf(fmaxf(smx[0], smx[1]), fmaxf(smx[2], smx[3]));
    float wreg = (t < NTS) ? __expf(v0 - m0) : 0.f;
    double W = (double)m0;
    __syncthreads();                                   // protect smx reuse

    const int j2 = t & 255;
    const int hh = t >> 8;
    for (int c = 0; c < 32; ++c) {
        const char* M0 = mats + (size_t)(2 * c) * SLOT2;
        const char* M1 = M0 + SLOT2;

        // sigma = max_r s_c[r]
        float sv = -INFINITY;
        if (t < NTS) sv = *(const float*)(((t < 128) ? M0 : M1) + 65536 + (t & 127) * 4);
        m = sv;
        #pragma unroll
        for (int off = 32; off; off >>= 1) m = fmaxf(m, __shfl_xor(m, off));
        if (lane == 0) smx[wv] = m;
        __syncthreads();                               // B1
        const float sigma = fmaxf(fmaxf(smx[0], smx[1]), fmaxf(smx[2], smx[3]));
        if (t < NTS) u[t] = __expf(sv - sigma) * wreg;
        __syncthreads();                               // B2

        // dot: thread (j2, hh) does half-row j2 of matrix half hh
        const char* Mh = hh ? M1 : M0;
        const uint4* rowp = (const uint4*)(Mh + (size_t)j2 * 256);
        const float* ub = u + hh * 128;
        float acc = 0.f;
        #pragma unroll
        for (int q = 0; q < 16; q++) {
            uint4 a = rowp[q];
            const float* uq = ub + q * 8;
            acc += bf2f((unsigned short)(a.x & 0xffffu)) * uq[0]
                 + bf2f((unsigned short)(a.x >> 16))     * uq[1]
                 + bf2f((unsigned short)(a.y & 0xffffu)) * uq[2]
                 + bf2f((unsigned short)(a.y >> 16))     * uq[3]
                 + bf2f((unsigned short)(a.z & 0xffffu)) * uq[4]
                 + bf2f((unsigned short)(a.z >> 16))     * uq[5]
                 + bf2f((unsigned short)(a.w & 0xffffu)) * uq[6]
                 + bf2f((unsigned short)(a.w >> 16))     * uq[7];
        }
        if (hh == 1) pu[j2] = acc;
        __syncthreads();                               // B3
        float v = -INFINITY;
        if (t < NTS) v = acc + pu[t];
        m = v;
        #pragma unroll
        for (int off = 32; off; off >>= 1) m = fmaxf(m, __shfl_xor(m, off));
        if (lane == 0) smx[wv] = m;
        __syncthreads();                               // B4
        const float mstep = fmaxf(fmaxf(smx[0], smx[1]), fmaxf(smx[2], smx[3]));
        W += (double)(sigma + __logf(mstep));
        if (t < NTS) wreg = v * (1.0f / mstep);
        __syncthreads();                               // B5
    }

    // ---- logZ = W + log(sum wreg); out = logZ - gold ---------------------
    float ssum = (t < NTS) ? wreg : 0.f;
    #pragma unroll
    for (int off = 32; off; off >>= 1) ssum += __shfl_down(ssum, off);
    if (lane == 0) smx[wv] = ssum;
    __syncthreads();
    if (t == 0) {
        float S = smx[0] + smx[1] + smx[2] + smx[3];
        float logZ = (float)(W + (double)__logf(S));
        float gold = 0.f;
        #pragma unroll
        for (int k = 0; k < 8; k++) gold += red[k];
        int y0 = y[0], yl = y[TLEN - 1];
        gold += BOS[y0] + EOS[yl] + emit[(TLEN - 1) * NTS + yl];
        out[0] = logZ - gold;
    }
}

// ===========================================================================
// Fallback serial path (verified) + gold kernel
// ===========================================================================
__global__ __launch_bounds__(256) void crf_prep(const float* __restrict__ trans,
                                                __half2* __restrict__ Qp) {
    int j = threadIdx.x, p = blockIdx.x;
    float a = __expf(trans[(2 * p) * NTS + j]);
    float b = __expf(trans[(2 * p + 1) * NTS + j]);
    Qp[p * NTS + j] = __floats2half2_rn(a, b);
}

__global__ __launch_bounds__(512) void crf_forward(
        const float* __restrict__ emit, const float* __restrict__ BOS,
        const __half2* __restrict__ Qp_g, float* __restrict__ logZ_out) {
    __shared__ __half2 Qp[128 * NTS];
    __shared__ alignas(16) float w[NTS];
    __shared__ float part[2][NTS];
    __shared__ float ebuf[2][NTS];
    __shared__ float wavemax[8];
    const int t = threadIdx.x, j = t & 255, q = t >> 8, lane = t & 63, wv = t >> 6;
    for (int idx = t; idx < 128 * NTS; idx += 512) Qp[idx] = Qp_g[idx];
    float anew = -INFINITY;
    if (t < NTS) anew = BOS[t] + emit[t];
    float ml = anew;
    #pragma unroll
    for (int off = 32; off; off >>= 1) ml = fmaxf(ml, __shfl_down(ml, off));
    if (lane == 0) wavemax[wv] = ml;
    __syncthreads();
    float mstep = fmaxf(fmaxf(wavemax[0], wavemax[1]), fmaxf(wavemax[2], wavemax[3]));
    double Macc = (double)mstep;
    if (t < NTS) w[t] = __expf(anew - mstep);
    float epre = 0.f;
    if (q == 1) epre = emit[NTS + j];
    __syncthreads();
    for (int i = 1; i < TLEN; ++i) {
        if (q == 1) ebuf[i & 1][j] = epre;
        float acc = 0.f;
        const __half2* qptr = Qp + (q * 64) * NTS + j;
        const float2* wptr = (const float2*)(w + q * 128);
        #pragma unroll 16
        for (int kk = 0; kk < 64; ++kk) {
            __half2 qv = qptr[kk * NTS];
            float2 wv2 = wptr[kk];
            acc += __low2float(qv) * wv2.x + __high2float(qv) * wv2.y;
        }
        part[q][j] = acc;
        if (q == 1 && (i + 1) < TLEN) epre = emit[(i + 1) * NTS + j];
        __syncthreads();
        float an = 0.f;
        ml = -INFINITY;
        if (t < NTS) {
            float vv = part[0][t] + part[1][t];
            an = ebuf[i & 1][t] + __logf(vv);
            ml = an;
        }
        #pragma unroll
        for (int off = 32; off; off >>= 1) ml = fmaxf(ml, __shfl_down(ml, off));
        if (lane == 0 && wv < 4) wavemax[wv] = ml;
        __syncthreads();
        mstep = fmaxf(fmaxf(wavemax[0], wavemax[1]), fmaxf(wavemax[2], wavemax[3]));
        Macc += (double)mstep;
        if (t < NTS) w[t] = __expf(an - mstep);
        __syncthreads();
    }
    float s = (t < NTS) ? w[t] : 0.f;
    #pragma unroll
    for (int off = 32; off; off >>= 1) s += __shfl_down(s, off);
    if (lane == 0 && wv < 4) wavemax[wv] = s;
    __syncthreads();
    if (t == 0) {
        float tot = wavemax[0] + wavemax[1] + wavemax[2] + wavemax[3];
        logZ_out[0] = (float)(Macc + (double)__logf(tot));
    }
}

__global__ __launch_bounds__(512) void crf_gold(
        const float* __restrict__ emit, const int* __restrict__ y,
        const float* __restrict__ trans, const float* __restrict__ BOS,
        const float* __restrict__ EOS, const float* __restrict__ logZ_ws,
        float* __restrict__ out) {
    __shared__ float red[8];
    int t = threadIdx.x;
    float s = 0.f;
    for (int i = t; i < TLEN - 1; i += 512) {
        int yi = y[i], yn = y[i + 1];
        s += trans[yi * NTS + yn] + emit[i * NTS + yi];
    }
    #pragma unroll
    for (int off = 32; off; off >>= 1) s += __shfl_down(s, off);
    if ((t & 63) == 0) red[t >> 6] = s;
    __syncthreads();
    if (t == 0) {
        float tot = 0.f;
        #pragma unroll
        for (int k2 = 0; k2 < 8; ++k2) tot += red[k2];
        int y0 = y[0], yl = y[TLEN - 1];
        tot += BOS[y0] + EOS[yl] + emit[(TLEN - 1) * NTS + yl];
        out[0] = logZ_ws[0] - tot;
    }
}

// ===========================================================================
extern "C" void kernel_launch(void* const* d_in, const int* in_sizes, int n_in,
                              void* d_out, int out_size, void* d_ws, size_t ws_size,
                              hipStream_t stream) {
    const float* emit  = (const float*)d_in[0];
    const int*   y     = (const int*)d_in[1];
    const float* trans = (const float*)d_in[2];
    const float* BOS   = (const float*)d_in[3];
    const float* EOS   = (const float*)d_in[4];
    float* out = (float*)d_out;

    const size_t need = (size_t)(512 + 256) * SLOT2 + 256;
    if (ws_size >= need) {
        char* X = (char*)d_ws;                       // 512 half-slots
        char* Y = X + (size_t)512 * SLOT2;           // 64 half-slots used

        crf_phase1<<<2 * NCH, 256, 0, stream>>>(emit, trans, X);
        crf_combine_run<<<64, 256, 0, stream>>>(X, Y);  // 256 -> 32 matrices
        crf_chainfin<<<1, 512, 0, stream>>>(Y, emit, BOS, y, trans, EOS, out);
    } else {
        __half2* Qp = (__half2*)d_ws;
        float* logZ = (float*)((char*)d_ws + 128 * NTS * sizeof(__half2));
        crf_prep<<<128, 256, 0, stream>>>(trans, Qp);
        crf_forward<<<1, 512, 0, stream>>>(emit, BOS, Qp, logZ);
        crf_gold<<<1, 512, 0, stream>>>(emit, y, trans, BOS, EOS, logZ, out);
    }
}

// Round 11
// 520.995 us; speedup vs baseline: 1.0558x; 1.0558x over previous
//
#include <hip/hip_runtime.h>
#include <hip/hip_fp16.h>
#include <hip/hip_cooperative_groups.h>

namespace cg = cooperative_groups;

#define TLEN 8192
#define NTS  256
#define CLEN 32
#define NCH  256           // TLEN / CLEN
#define SLOT2 66048        // 256*128 bf16 (65536) + 128 f32 scales (512)

typedef __bf16 bf16x8 __attribute__((ext_vector_type(8)));
typedef float  f32x4  __attribute__((ext_vector_type(4)));
union U128 { uint4 u; bf16x8 v; };
union U64  { uint2 u; long l; };

__device__ __forceinline__ unsigned f2bfu(float x) {
    unsigned u = __float_as_uint(x);
    return (u + 0x7fffu + ((u >> 16) & 1u)) >> 16;
}
__device__ __forceinline__ unsigned pk2(float lo, float hi) {
    return f2bfu(lo) | (f2bfu(hi) << 16);
}
__device__ __forceinline__ float bf2f(unsigned short h) {
    return __uint_as_float(((unsigned)h) << 16);
}
__device__ __forceinline__ unsigned pk4bf8(float a, float b, float c, float d) {
    int r = __builtin_amdgcn_cvt_pk_bf8_f32(a, b, 0, false);
    r = __builtin_amdgcn_cvt_pk_bf8_f32(c, d, r, true);
    return (unsigned)r;
}
__device__ __forceinline__ float dot8(uint4 a, const float* uq) {
    return bf2f((unsigned short)(a.x & 0xffffu)) * uq[0]
         + bf2f((unsigned short)(a.x >> 16))     * uq[1]
         + bf2f((unsigned short)(a.y & 0xffffu)) * uq[2]
         + bf2f((unsigned short)(a.y >> 16))     * uq[3]
         + bf2f((unsigned short)(a.z & 0xffffu)) * uq[4]
         + bf2f((unsigned short)(a.z >> 16))     * uq[5]
         + bf2f((unsigned short)(a.w & 0xffffu)) * uq[6]
         + bf2f((unsigned short)(a.w >> 16))     * uq[7];
}

// ===========================================================================
// Phase 1 (fp8): unchanged, proven (round 7-10). 224 us, MfmaUtil ~53%.
// ===========================================================================
__global__ __launch_bounds__(256, 2) void crf_phase1(
        const float* __restrict__ emit, const float* __restrict__ trans,
        char* __restrict__ outX) {
    __shared__ alignas(16) char qt8[65536];
    __shared__ alignas(16) char scr[4][1280];
    __shared__ alignas(16) float eld[2][NTS];

    const int t    = threadIdx.x;
    const int lane = t & 63;
    const int w    = t >> 6;
    const int gl   = lane >> 4;
    const int ln15 = lane & 15;
    const int c    = blockIdx.x >> 1;
    const int h    = blockIdx.x & 1;
    const int istart = (c == 0) ? 1 : CLEN * c;
    const int iend   = CLEN * c + CLEN;

    {
        const int ln = t & 15;
        for (int gk = 0; gk < 32; gk++) {
            float v[8];
            #pragma unroll
            for (int e = 0; e < 8; e++) v[e] = __expf(trans[(gk * 8 + e) * NTS + t]);
            uint2 u;
            u.x = pk4bf8(v[0], v[1], v[2], v[3]);
            u.y = pk4bf8(v[4], v[5], v[6], v[7]);
            const int p = (gk + 4 * ln + (ln >> 2)) & 31;
            *(uint2*)(qt8 + t * 256 + p * 8) = u;
        }
    }
    eld[istart & 1][t] = __expf(emit[istart * NTS + t]);

    int aoff[8];
    #pragma unroll
    for (int kf = 0; kf < 8; kf++) {
        const int p = (4 * kf + gl + 4 * ln15 + (ln15 >> 2)) & 31;
        aoff[kf] = ln15 * 256 + p * 8;
    }

    uint2 Bf[8][2];
    #pragma unroll
    for (int kf = 0; kf < 8; kf++)
        #pragma unroll
        for (int cb = 0; cb < 2; cb++) {
            uint2 bu; bu.x = 0u; bu.y = 0u;
            const int r_glob = 128 * h + 32 * w + cb * 16 + ln15;
            if ((r_glob >> 3) == kf * 4 + gl) {
                const int e = r_glob & 7;
                if (e < 4) bu.x = 0x3Cu << (8 * e);
                else       bu.y = 0x3Cu << (8 * (e - 4));
            }
            Bf[kf][cb] = bu;
        }
    float rs[2] = {0.f, 0.f};
    __syncthreads();

    char* const mysc = &scr[w][0];
    for (int i = istart; i < iend; ++i) {
        float enext = 0.f;
        if (i + 1 < iend) enext = emit[(i + 1) * NTS + t];

        f32x4 Cacc[16][2];
        #pragma unroll
        for (int jb = 0; jb < 16; jb++)
            #pragma unroll
            for (int cb = 0; cb < 2; cb++) Cacc[jb][cb] = f32x4{0.f, 0.f, 0.f, 0.f};

        #pragma unroll
        for (int jb = 0; jb < 16; jb++) {
            #pragma unroll
            for (int kf = 0; kf < 8; kf++) {
                U64 a; a.u = *(const uint2*)(qt8 + (aoff[kf] + jb * 4096));
                #pragma unroll
                for (int cb = 0; cb < 2; cb++) {
                    U64 b; b.u = Bf[kf][cb];
                    Cacc[jb][cb] = __builtin_amdgcn_mfma_f32_16x16x32_bf8_bf8(
                        a.l, b.l, Cacc[jb][cb], 0, 0, 0);
                }
            }
        }

        #pragma unroll
        for (int jb = 0; jb < 16; jb++) {
            float4 ev = *(const float4*)&eld[i & 1][jb * 16 + gl * 4];
            #pragma unroll
            for (int cb = 0; cb < 2; cb++) {
                Cacc[jb][cb][0] *= ev.x; Cacc[jb][cb][1] *= ev.y;
                Cacc[jb][cb][2] *= ev.z; Cacc[jb][cb][3] *= ev.w;
            }
        }
        float rn[2];
        #pragma unroll
        for (int cb = 0; cb < 2; cb++) {
            float m0 = Cacc[0][cb][0];
            #pragma unroll
            for (int jb = 0; jb < 16; jb++)
                #pragma unroll
                for (int rg = 0; rg < 4; rg++) m0 = fmaxf(m0, Cacc[jb][cb][rg]);
            m0 = fmaxf(m0, __shfl_xor(m0, 16));
            m0 = fmaxf(m0, __shfl_xor(m0, 32));
            rn[cb] = 1.0f / m0;
            rs[cb] += __logf(m0);
        }

        if (i == iend - 1) {
            __syncthreads();
            #pragma unroll
            for (int jb = 0; jb < 16; jb++)
                #pragma unroll
                for (int cb = 0; cb < 2; cb++) {
                    int rsl = w * 32 + cb * 16 + ln15;
                    #pragma unroll
                    for (int rg = 0; rg < 4; rg++) {
                        int j = jb * 16 + gl * 4 + rg;
                        *(unsigned short*)(qt8 + ((j * 128 + rsl) << 1)) =
                            (unsigned short)f2bfu(Cacc[jb][cb][rg] * rn[cb]);
                    }
                }
            __syncthreads();
            char* SO = outX + (size_t)(2 * c + h) * SLOT2;
            #pragma unroll
            for (int q = 0; q < 16; q++)
                *(uint4*)(SO + q * 4096 + t * 16) =
                    *(const uint4*)(qt8 + q * 4096 + t * 16);
            if (lane < 16) {
                #pragma unroll
                for (int cb = 0; cb < 2; cb++) {
                    int rsl = w * 32 + cb * 16 + lane;
                    *(float*)(SO + 65536 + rsl * 4) = rs[cb];
                }
            }
        } else {
            #pragma unroll
            for (int kf = 0; kf < 8; kf++) {
                #pragma unroll
                for (int jbb = 0; jbb < 2; jbb++) {
                    const int jb = 2 * kf + jbb;
                    #pragma unroll
                    for (int cb = 0; cb < 2; cb++) {
                        const int col = cb * 16 + ln15;
                        unsigned pk = pk4bf8(Cacc[jb][cb][0] * rn[cb],
                                             Cacc[jb][cb][1] * rn[cb],
                                             Cacc[jb][cb][2] * rn[cb],
                                             Cacc[jb][cb][3] * rn[cb]);
                        *(unsigned*)(mysc + col * 40 + jbb * 16 + gl * 4) = pk;
                    }
                }
                asm volatile("s_waitcnt lgkmcnt(0)" ::: "memory");
                __builtin_amdgcn_sched_barrier(0);
                #pragma unroll
                for (int cb = 0; cb < 2; cb++) {
                    const int col = cb * 16 + ln15;
                    Bf[kf][cb] = *(const uint2*)(mysc + col * 40 + gl * 8);
                }
                asm volatile("s_waitcnt lgkmcnt(0)" ::: "memory");
                __builtin_amdgcn_sched_barrier(0);
            }
            eld[(i + 1) & 1][t] = __expf(enext);
            __syncthreads();
        }
    }
}

// ===========================================================================
// Shared binary-combine body (round-9 crf_combine2, proven): out (p,h) =
// Later(2p+1) x Earlier(2p), columns [128h,128h+128), linear storage.
// ===========================================================================
__device__ __forceinline__ void combine_body(
        const char* __restrict__ inb, char* __restrict__ outb,
        int p, int h, char* qt, unsigned (*scr)[512],
        float* efac, float* smax,
        int t, int lane, int w, int gl, int ln15) {
    const char* SL0 = inb + (size_t)(4 * p + 2) * SLOT2;
    const char* SL1 = inb + (size_t)(4 * p + 3) * SLOT2;
    const char* SE  = inb + (size_t)(4 * p + h) * SLOT2;
    char* SO = outb + (size_t)(2 * p + h) * SLOT2;

    float sv = *(const float*)(((t < 128) ? SL0 : SL1) + 65536 + (t & 127) * 4);
    float m = sv;
    #pragma unroll
    for (int off = 32; off; off >>= 1) m = fmaxf(m, __shfl_xor(m, off));
    if (lane == 0) smax[w] = m;
    __syncthreads();
    const float sigma = fmaxf(fmaxf(smax[0], smax[1]), fmaxf(smax[2], smax[3]));
    efac[t] = __expf(sv - sigma);
    __syncthreads();

    for (int it = 0; it < 32; it++) {
        int off = it * 2048 + t * 8;
        int j = off >> 8, k = off & 255;
        const char* src = (k < 128) ? (SL0 + (size_t)(j * 128 + k) * 2)
                                    : (SL1 + (size_t)(j * 128 + (k - 128)) * 2);
        uint4 d = *(const uint4*)src;
        float4 e0 = *(const float4*)&efac[k];
        float4 e1 = *(const float4*)&efac[k + 4];
        float ef[8] = {e0.x, e0.y, e0.z, e0.w, e1.x, e1.y, e1.z, e1.w};
        unsigned wds[4] = {d.x, d.y, d.z, d.w};
        unsigned outw[4];
        #pragma unroll
        for (int wi = 0; wi < 4; wi++) {
            float lo = bf2f((unsigned short)(wds[wi] & 0xffffu)) * ef[2 * wi];
            float hi = bf2f((unsigned short)(wds[wi] >> 16)) * ef[2 * wi + 1];
            outw[wi] = pk2(lo, hi);
        }
        uint4 o; o.x = outw[0]; o.y = outw[1]; o.z = outw[2]; o.w = outw[3];
        *(uint4*)(qt + ((j * 512 + k * 2) ^ ((j & 7) << 4))) = o;
    }

    bf16x8 Bf[8][2];
    #pragma unroll
    for (int kf = 0; kf < 8; kf++) {
        #pragma unroll
        for (int p2 = 0; p2 < 2; p2++) {
            int kk = p2 * 16 + (lane >> 2);
            uint4 d = *(const uint4*)(SE + (size_t)(32 * kf + kk) * 256
                                      + w * 64 + (lane & 3) * 16);
            *(uint4*)((char*)&scr[w][0] + kk * 64 + (lane & 3) * 16) = d;
        }
        asm volatile("s_waitcnt lgkmcnt(0)" ::: "memory");
        __builtin_amdgcn_sched_barrier(0);
        #pragma unroll
        for (int cb = 0; cb < 2; cb++) {
            unsigned wd[4] = {0u, 0u, 0u, 0u};
            #pragma unroll
            for (int e = 0; e < 8; e++) {
                int kloc = gl * 8 + e;
                unsigned short hh = *(const unsigned short*)
                    ((const char*)&scr[w][0] + kloc * 64 + (cb * 16 + ln15) * 2);
                wd[e >> 1] |= ((unsigned)hh) << (16 * (e & 1));
            }
            U128 q; q.u.x = wd[0]; q.u.y = wd[1]; q.u.z = wd[2]; q.u.w = wd[3];
            Bf[kf][cb] = q.v;
        }
        asm volatile("s_waitcnt lgkmcnt(0)" ::: "memory");
        __builtin_amdgcn_sched_barrier(0);
    }
    __syncthreads();

    f32x4 Cacc[16][2];
    #pragma unroll
    for (int jb = 0; jb < 16; jb++)
        #pragma unroll
        for (int cb = 0; cb < 2; cb++) Cacc[jb][cb] = f32x4{0.f, 0.f, 0.f, 0.f};
    const int aswz = (lane & 7) << 4;
    #pragma unroll
    for (int jb = 0; jb < 16; jb++) {
        const int abase = (jb * 16 + ln15) * 512 + gl * 16;
        #pragma unroll
        for (int kf = 0; kf < 8; kf++) {
            U128 a; a.u = *(const uint4*)(qt + ((abase + kf * 64) ^ aswz));
            #pragma unroll
            for (int cb = 0; cb < 2; cb++)
                Cacc[jb][cb] = __builtin_amdgcn_mfma_f32_16x16x32_bf16(
                    a.v, Bf[kf][cb], Cacc[jb][cb], 0, 0, 0);
        }
    }

    float mx[2], rn[2];
    #pragma unroll
    for (int cb = 0; cb < 2; cb++) {
        float m0 = Cacc[0][cb][0];
        #pragma unroll
        for (int jb = 0; jb < 16; jb++)
            #pragma unroll
            for (int rg = 0; rg < 4; rg++) m0 = fmaxf(m0, Cacc[jb][cb][rg]);
        m0 = fmaxf(m0, __shfl_xor(m0, 16));
        m0 = fmaxf(m0, __shfl_xor(m0, 32));
        mx[cb] = m0; rn[cb] = 1.0f / m0;
    }

    __syncthreads();
    #pragma unroll
    for (int jb = 0; jb < 16; jb++)
        #pragma unroll
        for (int cb = 0; cb < 2; cb++) {
            int rsl = w * 32 + cb * 16 + ln15;
            #pragma unroll
            for (int rg = 0; rg < 4; rg++) {
                int j = jb * 16 + gl * 4 + rg;
                *(unsigned short*)(qt + ((j * 128 + rsl) << 1)) =
                    (unsigned short)f2bfu(Cacc[jb][cb][rg] * rn[cb]);
            }
        }
    __syncthreads();
    #pragma unroll
    for (int q = 0; q < 16; q++)
        *(uint4*)(SO + q * 4096 + t * 16) = *(const uint4*)(qt + q * 4096 + t * 16);
    if (lane < 16) {
        #pragma unroll
        for (int cb = 0; cb < 2; cb++) {
            int rsl = w * 32 + cb * 16 + lane;
            float se = *(const float*)(SE + 65536 + rsl * 4);
            *(float*)(SO + 65536 + rsl * 4) = se + sigma + __logf(mx[cb]);
        }
    }
}

// ===========================================================================
// Cooperative tail: 4 binary levels (256->16 mats) with grid.sync between,
// gold partials in idle blocks during level 1, then block 0 runs the 16-step
// hot vector chain + finalize.  Grid 256 x 256, 1 block/CU.
// ===========================================================================
__global__ __launch_bounds__(256, 1) void crf_tail(
        char* X, char* Y, const float* emit, const float* BOS,
        const int* y, const float* trans, const float* EOS,
        float* goldws, float* out) {
    __shared__ alignas(16) char qt[131072];
    __shared__ alignas(16) unsigned scr[4][512];
    __shared__ alignas(16) float efac[NTS];
    __shared__ float smax[4];
    __shared__ alignas(16) float u[NTS];

    cg::grid_group grid = cg::this_grid();
    const int b = blockIdx.x;
    const int t = threadIdx.x;
    const int lane = t & 63;
    const int w = t >> 6;
    const int gl = lane >> 4;
    const int ln15 = lane & 15;

    for (int l = 0; l < 4; ++l) {
        char* inb  = (l & 1) ? Y : X;
        char* outb = (l & 1) ? X : Y;
        const int nin = 256 >> l;
        if (b < nin) {
            combine_body(inb, outb, b >> 1, b & 1, qt, scr, efac, smax,
                         t, lane, w, gl, ln15);
        } else if (l == 1) {
            // gold partials in idle blocks 128..255 (overlapped with level 1)
            float s = 0.f;
            if (t < 64) {
                int i = (b - 128) * 64 + t;
                if (i < TLEN - 1)
                    s = trans[y[i] * NTS + y[i + 1]] + emit[i * NTS + y[i]];
                #pragma unroll
                for (int off = 32; off; off >>= 1) s += __shfl_down(s, off);
                if (t == 0) goldws[b - 128] = s;
            }
        }
        grid.sync();
    }

    // ---- block 0: 16-step vector chain over hot matrices in X ------------
    if (b == 0) {
        float v0 = BOS[t] + emit[t];
        float m = v0;
        #pragma unroll
        for (int off = 32; off; off >>= 1) m = fmaxf(m, __shfl_xor(m, off));
        if (lane == 0) smax[w] = m;
        __syncthreads();
        const float m0 = fmaxf(fmaxf(smax[0], smax[1]), fmaxf(smax[2], smax[3]));
        float wreg = __expf(v0 - m0);
        double W = (double)m0;
        __syncthreads();

        for (int c = 0; c < 16; ++c) {
            const char* M0 = X + (size_t)(2 * c) * SLOT2;
            const char* M1 = M0 + SLOT2;

            float sv = *(const float*)(((t < 128) ? M0 : M1) + 65536 + (t & 127) * 4);
            m = sv;
            #pragma unroll
            for (int off = 32; off; off >>= 1) m = fmaxf(m, __shfl_xor(m, off));
            if (lane == 0) smax[w] = m;
            __syncthreads();
            const float sigma = fmaxf(fmaxf(smax[0], smax[1]),
                                      fmaxf(smax[2], smax[3]));
            u[t] = __expf(sv - sigma) * wreg;
            __syncthreads();

            const uint4* r0 = (const uint4*)(M0 + (size_t)t * 256);
            const uint4* r1 = (const uint4*)(M1 + (size_t)t * 256);
            float acc = 0.f;
            #pragma unroll
            for (int q = 0; q < 16; q++) acc += dot8(r0[q], &u[q * 8]);
            #pragma unroll
            for (int q = 0; q < 16; q++) acc += dot8(r1[q], &u[128 + q * 8]);

            m = acc;
            #pragma unroll
            for (int off = 32; off; off >>= 1) m = fmaxf(m, __shfl_xor(m, off));
            if (lane == 0) smax[w] = m;
            __syncthreads();
            const float mstep = fmaxf(fmaxf(smax[0], smax[1]),
                                      fmaxf(smax[2], smax[3]));
            W += (double)(sigma + __logf(mstep));
            wreg = acc * (1.0f / mstep);
            __syncthreads();
        }

        float ssum = wreg;
        #pragma unroll
        for (int off = 32; off; off >>= 1) ssum += __shfl_down(ssum, off);
        if (lane == 0) smax[w] = ssum;
        __syncthreads();
        if (t == 0) {
            float S = smax[0] + smax[1] + smax[2] + smax[3];
            float logZ = (float)(W + (double)__logf(S));
            float gold = 0.f;
            for (int k = 0; k < 128; k++) gold += goldws[k];
            int y0 = y[0], yl = y[TLEN - 1];
            gold += BOS[y0] + EOS[yl] + emit[(TLEN - 1) * NTS + yl];
            out[0] = logZ - gold;
        }
    }
}

// ===========================================================================
// Non-cooperative fallback tail (round-9, proven, 410 us total)
// ===========================================================================
__global__ __launch_bounds__(256, 1) void crf_combine2(
        const char* __restrict__ inb, char* __restrict__ outb) {
    __shared__ alignas(16) char qt[131072];
    __shared__ alignas(16) unsigned scr[4][512];
    __shared__ alignas(16) float efac[NTS];
    __shared__ float smax[4];
    const int t = threadIdx.x;
    combine_body(inb, outb, blockIdx.x >> 1, blockIdx.x & 1, qt, scr, efac, smax,
                 t, t & 63, t >> 6, (t & 63) >> 4, t & 15);
}

__global__ __launch_bounds__(512) void crf_chainfin16(
        const char* __restrict__ mats, const float* __restrict__ emit,
        const float* __restrict__ BOS, const int* __restrict__ y,
        const float* __restrict__ trans, const float* __restrict__ EOS,
        float* __restrict__ out) {
    __shared__ float red[8];
    __shared__ float smx[8];
    __shared__ alignas(16) float u[NTS];
    __shared__ float pu[NTS];
    const int t = threadIdx.x, lane = t & 63, wv = t >> 6;

    float s = 0.f;
    for (int i = t; i < TLEN - 1; i += 512) {
        int yi = y[i], yn = y[i + 1];
        s += trans[yi * NTS + yn] + emit[i * NTS + yi];
    }
    #pragma unroll
    for (int off = 32; off; off >>= 1) s += __shfl_down(s, off);
    if (lane == 0) red[wv] = s;

    float v0 = (t < NTS) ? (BOS[t] + emit[t]) : -INFINITY;
    float m = v0;
    #pragma unroll
    for (int off = 32; off; off >>= 1) m = fmaxf(m, __shfl_xor(m, off));
    if (lane == 0) smx[wv] = m;
    __syncthreads();
    const float m0 = fmaxf(fmaxf(smx[0], smx[1]), fmaxf(smx[2], smx[3]));
    float wreg = (t < NTS) ? __expf(v0 - m0) : 0.f;
    double W = (double)m0;
    __syncthreads();

    const int j2 = t & 255;
    const int hh = t >> 8;
    for (int c = 0; c < 16; ++c) {
        const char* M0 = mats + (size_t)(2 * c) * SLOT2;
        const char* M1 = M0 + SLOT2;
        float sv = -INFINITY;
        if (t < NTS) sv = *(const float*)(((t < 128) ? M0 : M1) + 65536 + (t & 127) * 4);
        m = sv;
        #pragma unroll
        for (int off = 32; off; off >>= 1) m = fmaxf(m, __shfl_xor(m, off));
        if (lane == 0) smx[wv] = m;
        __syncthreads();
        const float sigma = fmaxf(fmaxf(smx[0], smx[1]), fmaxf(smx[2], smx[3]));
        if (t < NTS) u[t] = __expf(sv - sigma) * wreg;
        __syncthreads();

        const char* Mh = hh ? M1 : M0;
        const uint4* rowp = (const uint4*)(Mh + (size_t)j2 * 256);
        const float* ub = u + hh * 128;
        float acc = 0.f;
        #pragma unroll
        for (int q = 0; q < 16; q++) acc += dot8(rowp[q], ub + q * 8);
        if (hh == 1) pu[j2] = acc;
        __syncthreads();
        float v = -INFINITY;
        if (t < NTS) v = acc + pu[t];
        m = v;
        #pragma unroll
        for (int off = 32; off; off >>= 1) m = fmaxf(m, __shfl_xor(m, off));
        if (lane == 0) smx[wv] = m;
        __syncthreads();
        const float mstep = fmaxf(fmaxf(smx[0], smx[1]), fmaxf(smx[2], smx[3]));
        W += (double)(sigma + __logf(mstep));
        if (t < NTS) wreg = v * (1.0f / mstep);
        __syncthreads();
    }

    float ssum = (t < NTS) ? wreg : 0.f;
    #pragma unroll
    for (int off = 32; off; off >>= 1) ssum += __shfl_down(ssum, off);
    if (lane == 0) smx[wv] = ssum;
    __syncthreads();
    if (t == 0) {
        float S = smx[0] + smx[1] + smx[2] + smx[3];
        float logZ = (float)(W + (double)__logf(S));
        float gold = 0.f;
        #pragma unroll
        for (int k = 0; k < 8; k++) gold += red[k];
        int y0 = y[0], yl = y[TLEN - 1];
        gold += BOS[y0] + EOS[yl] + emit[(TLEN - 1) * NTS + yl];
        out[0] = logZ - gold;
    }
}

// ===========================================================================
// Serial fallback (ws too small) — unchanged, verified
// ===========================================================================
__global__ __launch_bounds__(256) void crf_prep(const float* __restrict__ trans,
                                                __half2* __restrict__ Qp) {
    int j = threadIdx.x, p = blockIdx.x;
    float a = __expf(trans[(2 * p) * NTS + j]);
    float b = __expf(trans[(2 * p + 1) * NTS + j]);
    Qp[p * NTS + j] = __floats2half2_rn(a, b);
}

__global__ __launch_bounds__(512) void crf_forward(
        const float* __restrict__ emit, const float* __restrict__ BOS,
        const __half2* __restrict__ Qp_g, float* __restrict__ logZ_out) {
    __shared__ __half2 Qp[128 * NTS];
    __shared__ alignas(16) float w[NTS];
    __shared__ float part[2][NTS];
    __shared__ float ebuf[2][NTS];
    __shared__ float wavemax[8];
    const int t = threadIdx.x, j = t & 255, q = t >> 8, lane = t & 63, wv = t >> 6;
    for (int idx = t; idx < 128 * NTS; idx += 512) Qp[idx] = Qp_g[idx];
    float anew = -INFINITY;
    if (t < NTS) anew = BOS[t] + emit[t];
    float ml = anew;
    #pragma unroll
    for (int off = 32; off; off >>= 1) ml = fmaxf(ml, __shfl_down(ml, off));
    if (lane == 0) wavemax[wv] = ml;
    __syncthreads();
    float mstep = fmaxf(fmaxf(wavemax[0], wavemax[1]), fmaxf(wavemax[2], wavemax[3]));
    double Macc = (double)mstep;
    if (t < NTS) w[t] = __expf(anew - mstep);
    float epre = 0.f;
    if (q == 1) epre = emit[NTS + j];
    __syncthreads();
    for (int i = 1; i < TLEN; ++i) {
        if (q == 1) ebuf[i & 1][j] = epre;
        float acc = 0.f;
        const __half2* qptr = Qp + (q * 64) * NTS + j;
        const float2* wptr = (const float2*)(w + q * 128);
        #pragma unroll 16
        for (int kk = 0; kk < 64; ++kk) {
            __half2 qv = qptr[kk * NTS];
            float2 wv2 = wptr[kk];
            acc += __low2float(qv) * wv2.x + __high2float(qv) * wv2.y;
        }
        part[q][j] = acc;
        if (q == 1 && (i + 1) < TLEN) epre = emit[(i + 1) * NTS + j];
        __syncthreads();
        float an = 0.f;
        ml = -INFINITY;
        if (t < NTS) {
            float vv = part[0][t] + part[1][t];
            an = ebuf[i & 1][t] + __logf(vv);
            ml = an;
        }
        #pragma unroll
        for (int off = 32; off; off >>= 1) ml = fmaxf(ml, __shfl_down(ml, off));
        if (lane == 0 && wv < 4) wavemax[wv] = ml;
        __syncthreads();
        mstep = fmaxf(fmaxf(wavemax[0], wavemax[1]), fmaxf(wavemax[2], wavemax[3]));
        Macc += (double)mstep;
        if (t < NTS) w[t] = __expf(an - mstep);
        __syncthreads();
    }
    float s = (t < NTS) ? w[t] : 0.f;
    #pragma unroll
    for (int off = 32; off; off >>= 1) s += __shfl_down(s, off);
    if (lane == 0 && wv < 4) wavemax[wv] = s;
    __syncthreads();
    if (t == 0) {
        float tot = wavemax[0] + wavemax[1] + wavemax[2] + wavemax[3];
        logZ_out[0] = (float)(Macc + (double)__logf(tot));
    }
}

__global__ __launch_bounds__(512) void crf_gold(
        const float* __restrict__ emit, const int* __restrict__ y,
        const float* __restrict__ trans, const float* __restrict__ BOS,
        const float* __restrict__ EOS, const float* __restrict__ logZ_ws,
        float* __restrict__ out) {
    __shared__ float red[8];
    int t = threadIdx.x;
    float s = 0.f;
    for (int i = t; i < TLEN - 1; i += 512) {
        int yi = y[i], yn = y[i + 1];
        s += trans[yi * NTS + yn] + emit[i * NTS + yi];
    }
    #pragma unroll
    for (int off = 32; off; off >>= 1) s += __shfl_down(s, off);
    if ((t & 63) == 0) red[t >> 6] = s;
    __syncthreads();
    if (t == 0) {
        float tot = 0.f;
        #pragma unroll
        for (int k2 = 0; k2 < 8; ++k2) tot += red[k2];
        int y0 = y[0], yl = y[TLEN - 1];
        tot += BOS[y0] + EOS[yl] + emit[(TLEN - 1) * NTS + yl];
        out[0] = logZ_ws[0] - tot;
    }
}

// ===========================================================================
extern "C" void kernel_launch(void* const* d_in, const int* in_sizes, int n_in,
                              void* d_out, int out_size, void* d_ws, size_t ws_size,
                              hipStream_t stream) {
    const float* emit  = (const float*)d_in[0];
    const int*   y     = (const int*)d_in[1];
    const float* trans = (const float*)d_in[2];
    const float* BOS   = (const float*)d_in[3];
    const float* EOS   = (const float*)d_in[4];
    float* out = (float*)d_out;

    const size_t need = (size_t)(512 + 256) * SLOT2 + 1024;
    if (ws_size >= need) {
        char* X = (char*)d_ws;                        // 512 half-slots
        char* Y = X + (size_t)512 * SLOT2;            // 256 half-slots
        float* goldws = (float*)(Y + (size_t)256 * SLOT2);   // 128 floats

        crf_phase1<<<2 * NCH, 256, 0, stream>>>(emit, trans, X);

        void* args[] = { &X, &Y, (void*)&emit, (void*)&BOS, (void*)&y,
                         (void*)&trans, (void*)&EOS, &goldws, &out };
        hipError_t e = hipLaunchCooperativeKernel(
            (void*)crf_tail, dim3(256), dim3(256), args, 0, stream);
        if (e != hipSuccess) {
            // proven round-9 tail
            crf_combine2<<<256, 256, 0, stream>>>(X, Y);
            crf_combine2<<<128, 256, 0, stream>>>(Y, X);
            crf_combine2<<<64, 256, 0, stream>>>(X, Y);
            crf_combine2<<<32, 256, 0, stream>>>(Y, X);
            crf_chainfin16<<<1, 512, 0, stream>>>(X, emit, BOS, y, trans, EOS, out);
        }
    } else {
        __half2* Qp = (__half2*)d_ws;
        float* logZ = (float*)((char*)d_ws + 128 * NTS * sizeof(__half2));
        crf_prep<<<128, 256, 0, stream>>>(trans, Qp);
        crf_forward<<<1, 512, 0, stream>>>(emit, BOS, Qp, logZ);
        crf_gold<<<1, 512, 0, stream>>>(emit, y, trans, BOS, EOS, logZ, out);
    }
}

// Round 14
// 458.183 us; speedup vs baseline: 1.2006x; 1.1371x over previous
//
#include <hip/hip_runtime.h>
#include <hip/hip_fp16.h>

#define TLEN 8192
#define NTS  256
#define CLEN 32
#define NCH  256           // TLEN / CLEN
#define SLOT2 66048        // 256*128 bf16 (65536) + 128 f32 scales (512)

typedef __bf16 bf16x8 __attribute__((ext_vector_type(8)));
typedef float  f32x4  __attribute__((ext_vector_type(4)));
union U128 { uint4 u; bf16x8 v; };
union U64  { uint2 u; long l; };

__device__ __forceinline__ unsigned f2bfu(float x) {
    unsigned u = __float_as_uint(x);
    return (u + 0x7fffu + ((u >> 16) & 1u)) >> 16;
}
__device__ __forceinline__ unsigned pk2(float lo, float hi) {
    return f2bfu(lo) | (f2bfu(hi) << 16);
}
__device__ __forceinline__ float bf2f(unsigned short h) {
    return __uint_as_float(((unsigned)h) << 16);
}
__device__ __forceinline__ unsigned pk4bf8(float a, float b, float c, float d) {
    int r = __builtin_amdgcn_cvt_pk_bf8_f32(a, b, 0, false);
    r = __builtin_amdgcn_cvt_pk_bf8_f32(c, d, r, true);
    return (unsigned)r;
}
__device__ __forceinline__ float dot8(uint4 a, const float* uq) {
    return bf2f((unsigned short)(a.x & 0xffffu)) * uq[0]
         + bf2f((unsigned short)(a.x >> 16))     * uq[1]
         + bf2f((unsigned short)(a.y & 0xffffu)) * uq[2]
         + bf2f((unsigned short)(a.y >> 16))     * uq[3]
         + bf2f((unsigned short)(a.z & 0xffffu)) * uq[4]
         + bf2f((unsigned short)(a.z >> 16))     * uq[5]
         + bf2f((unsigned short)(a.w & 0xffffu)) * uq[6]
         + bf2f((unsigned short)(a.w >> 16))     * uq[7];
}

// ===========================================================================
// Phase 1 (fp8, 8-wave): block = (chunk c, col-half h), 512 thr = 8 waves,
// wave owns 16 columns (Cacc 64 VGPR + Bf 16 -> fits 128 cap at 2 blocks/CU
// = 4 waves/SIMD from two independent blocks -> stalls hidden).
// Q in LDS as bf8 e5m2 (64 KiB). Output LINEAR bf16 + f32 column log scales.
// ===========================================================================
__global__ __launch_bounds__(512, 2) void crf_phase1(
        const float* __restrict__ emit, const float* __restrict__ trans,
        char* __restrict__ outX) {
    __shared__ alignas(16) char qt8[65536];      // QT[j][k] bf8, granule-rotated
    __shared__ alignas(16) char scr[8][640];     // exchange: 16 cols x 40 B/wave
    __shared__ alignas(16) float eld[2][NTS];    // exp(emit row), dbuf

    const int t    = threadIdx.x;
    const int lane = t & 63;
    const int w    = t >> 6;              // 0..7
    const int gl   = lane >> 4;           // 0..3
    const int ln15 = lane & 15;
    const int c    = blockIdx.x >> 1;
    const int h    = blockIdx.x & 1;
    const int istart = (c == 0) ? 1 : CLEN * c;
    const int iend   = CLEN * c + CLEN;

    // ---- stage QT[j][k] = exp(trans[k][j]) as bf8, rotated granules ------
    {
        const int tt  = t & 255;          // column j
        const int hlf = t >> 8;           // granule half
        const int ln  = tt & 15;
        for (int gk = hlf * 16; gk < hlf * 16 + 16; gk++) {
            float v[8];
            #pragma unroll
            for (int e = 0; e < 8; e++) v[e] = __expf(trans[(gk * 8 + e) * NTS + tt]);
            uint2 u;
            u.x = pk4bf8(v[0], v[1], v[2], v[3]);
            u.y = pk4bf8(v[4], v[5], v[6], v[7]);
            const int p = (gk + 4 * ln + (ln >> 2)) & 31;
            *(uint2*)(qt8 + tt * 256 + p * 8) = u;
        }
    }
    if (t < NTS) eld[istart & 1][t] = __expf(emit[istart * NTS + t]);

    int aoff[8];
    #pragma unroll
    for (int kf = 0; kf < 8; kf++) {
        const int p = (4 * kf + gl + 4 * ln15 + (ln15 >> 2)) & 31;
        aoff[kf] = ln15 * 256 + p * 8;
    }

    // ---- B := Identity columns (bf8 1.0 = 0x3C), rs := 0 -----------------
    const int rsl    = w * 16 + ln15;         // local col 0..127
    const int r_glob = 128 * h + rsl;         // global col
    uint2 Bf[8];
    #pragma unroll
    for (int kf = 0; kf < 8; kf++) {
        uint2 bu; bu.x = 0u; bu.y = 0u;
        if ((r_glob >> 3) == kf * 4 + gl) {
            const int e = r_glob & 7;
            if (e < 4) bu.x = 0x3Cu << (8 * e);
            else       bu.y = 0x3Cu << (8 * (e - 4));
        }
        Bf[kf] = bu;
    }
    float rs = 0.f;
    __syncthreads();

    char* const mysc = &scr[w][0];
    for (int i = istart; i < iend; ++i) {
        float enext = 0.f;
        if (t < NTS && i + 1 < iend) enext = emit[(i + 1) * NTS + t];

        // ---- C = QT * B (bf8 MFMA, 128 per wave-step) ---------------------
        f32x4 Cacc[16];
        #pragma unroll
        for (int jb = 0; jb < 16; jb++) Cacc[jb] = f32x4{0.f, 0.f, 0.f, 0.f};

        #pragma unroll
        for (int jb = 0; jb < 16; jb++) {
            #pragma unroll
            for (int kf = 0; kf < 8; kf++) {
                U64 a; a.u = *(const uint2*)(qt8 + (aoff[kf] + jb * 4096));
                U64 b; b.u = Bf[kf];
                Cacc[jb] = __builtin_amdgcn_mfma_f32_16x16x32_bf8_bf8(
                    a.l, b.l, Cacc[jb], 0, 0, 0);
            }
        }

        // ---- scale rows j by exp(emit[i][j]) ------------------------------
        #pragma unroll
        for (int jb = 0; jb < 16; jb++) {
            float4 ev = *(const float4*)&eld[i & 1][jb * 16 + gl * 4];
            Cacc[jb][0] *= ev.x; Cacc[jb][1] *= ev.y;
            Cacc[jb][2] *= ev.z; Cacc[jb][3] *= ev.w;
        }
        // ---- per-column max + renormalize ---------------------------------
        float m0 = Cacc[0][0];
        #pragma unroll
        for (int jb = 0; jb < 16; jb++)
            #pragma unroll
            for (int rg = 0; rg < 4; rg++) m0 = fmaxf(m0, Cacc[jb][rg]);
        m0 = fmaxf(m0, __shfl_xor(m0, 16));
        m0 = fmaxf(m0, __shfl_xor(m0, 32));
        const float rn = 1.0f / m0;
        rs += __logf(m0);

        if (i == iend - 1) {
            // ---- coalesced write: scatter into qt8 (dead), then copy out ---
            __syncthreads();              // all waves done reading qt8 (MFMA)
            #pragma unroll
            for (int jb = 0; jb < 16; jb++) {
                #pragma unroll
                for (int rg = 0; rg < 4; rg++) {
                    int j = jb * 16 + gl * 4 + rg;
                    *(unsigned short*)(qt8 + ((j * 128 + rsl) << 1)) =
                        (unsigned short)f2bfu(Cacc[jb][rg] * rn);
                }
            }
            __syncthreads();
            char* SO = outX + (size_t)(2 * c + h) * SLOT2;
            #pragma unroll
            for (int q = 0; q < 8; q++)
                *(uint4*)(SO + q * 8192 + t * 16) =
                    *(const uint4*)(qt8 + q * 8192 + t * 16);
            if (gl == 0) *(float*)(SO + 65536 + rsl * 4) = rs;
        } else {
            // ---- C -> next B (bf8) via intra-wave LDS exchange -------------
            #pragma unroll
            for (int kf = 0; kf < 8; kf++) {
                #pragma unroll
                for (int jbb = 0; jbb < 2; jbb++) {
                    const int jb = 2 * kf + jbb;
                    unsigned pk = pk4bf8(Cacc[jb][0] * rn, Cacc[jb][1] * rn,
                                         Cacc[jb][2] * rn, Cacc[jb][3] * rn);
                    *(unsigned*)(mysc + ln15 * 40 + jbb * 16 + gl * 4) = pk;
                }
                asm volatile("s_waitcnt lgkmcnt(0)" ::: "memory");
                __builtin_amdgcn_sched_barrier(0);
                Bf[kf] = *(const uint2*)(mysc + ln15 * 40 + gl * 8);
                asm volatile("s_waitcnt lgkmcnt(0)" ::: "memory");
                __builtin_amdgcn_sched_barrier(0);
            }
            if (t < NTS) eld[(i + 1) & 1][t] = __expf(enext);
            __syncthreads();
        }
    }
}

// ===========================================================================
// Binary-combine body (round-9, proven): out (p,h) = Later(2p+1) x
// Earlier(2p), columns [128h,128h+128), linear storage.
// ===========================================================================
__device__ __forceinline__ void combine_body(
        const char* __restrict__ inb, char* __restrict__ outb,
        int p, int h, char* qt, unsigned (*scr)[512],
        float* efac, float* smax,
        int t, int lane, int w, int gl, int ln15) {
    const char* SL0 = inb + (size_t)(4 * p + 2) * SLOT2;
    const char* SL1 = inb + (size_t)(4 * p + 3) * SLOT2;
    const char* SE  = inb + (size_t)(4 * p + h) * SLOT2;
    char* SO = outb + (size_t)(2 * p + h) * SLOT2;

    float sv = *(const float*)(((t < 128) ? SL0 : SL1) + 65536 + (t & 127) * 4);
    float m = sv;
    #pragma unroll
    for (int off = 32; off; off >>= 1) m = fmaxf(m, __shfl_xor(m, off));
    if (lane == 0) smax[w] = m;
    __syncthreads();
    const float sigma = fmaxf(fmaxf(smax[0], smax[1]), fmaxf(smax[2], smax[3]));
    efac[t] = __expf(sv - sigma);
    __syncthreads();

    for (int it = 0; it < 32; it++) {
        int off = it * 2048 + t * 8;
        int j = off >> 8, k = off & 255;
        const char* src = (k < 128) ? (SL0 + (size_t)(j * 128 + k) * 2)
                                    : (SL1 + (size_t)(j * 128 + (k - 128)) * 2);
        uint4 d = *(const uint4*)src;
        float4 e0 = *(const float4*)&efac[k];
        float4 e1 = *(const float4*)&efac[k + 4];
        float ef[8] = {e0.x, e0.y, e0.z, e0.w, e1.x, e1.y, e1.z, e1.w};
        unsigned wds[4] = {d.x, d.y, d.z, d.w};
        unsigned outw[4];
        #pragma unroll
        for (int wi = 0; wi < 4; wi++) {
            float lo = bf2f((unsigned short)(wds[wi] & 0xffffu)) * ef[2 * wi];
            float hi = bf2f((unsigned short)(wds[wi] >> 16)) * ef[2 * wi + 1];
            outw[wi] = pk2(lo, hi);
        }
        uint4 o; o.x = outw[0]; o.y = outw[1]; o.z = outw[2]; o.w = outw[3];
        *(uint4*)(qt + ((j * 512 + k * 2) ^ ((j & 7) << 4))) = o;
    }

    bf16x8 Bf[8][2];
    #pragma unroll
    for (int kf = 0; kf < 8; kf++) {
        #pragma unroll
        for (int p2 = 0; p2 < 2; p2++) {
            int kk = p2 * 16 + (lane >> 2);
            uint4 d = *(const uint4*)(SE + (size_t)(32 * kf + kk) * 256
                                      + w * 64 + (lane & 3) * 16);
            *(uint4*)((char*)&scr[w][0] + kk * 64 + (lane & 3) * 16) = d;
        }
        asm volatile("s_waitcnt lgkmcnt(0)" ::: "memory");
        __builtin_amdgcn_sched_barrier(0);
        #pragma unroll
        for (int cb = 0; cb < 2; cb++) {
            unsigned wd[4] = {0u, 0u, 0u, 0u};
            #pragma unroll
            for (int e = 0; e < 8; e++) {
                int kloc = gl * 8 + e;
                unsigned short hh = *(const unsigned short*)
                    ((const char*)&scr[w][0] + kloc * 64 + (cb * 16 + ln15) * 2);
                wd[e >> 1] |= ((unsigned)hh) << (16 * (e & 1));
            }
            U128 q; q.u.x = wd[0]; q.u.y = wd[1]; q.u.z = wd[2]; q.u.w = wd[3];
            Bf[kf][cb] = q.v;
        }
        asm volatile("s_waitcnt lgkmcnt(0)" ::: "memory");
        __builtin_amdgcn_sched_barrier(0);
    }
    __syncthreads();

    f32x4 Cacc[16][2];
    #pragma unroll
    for (int jb = 0; jb < 16; jb++)
        #pragma unroll
        for (int cb = 0; cb < 2; cb++) Cacc[jb][cb] = f32x4{0.f, 0.f, 0.f, 0.f};
    const int aswz = (lane & 7) << 4;
    #pragma unroll
    for (int jb = 0; jb < 16; jb++) {
        const int abase = (jb * 16 + ln15) * 512 + gl * 16;
        #pragma unroll
        for (int kf = 0; kf < 8; kf++) {
            U128 a; a.u = *(const uint4*)(qt + ((abase + kf * 64) ^ aswz));
            #pragma unroll
            for (int cb = 0; cb < 2; cb++)
                Cacc[jb][cb] = __builtin_amdgcn_mfma_f32_16x16x32_bf16(
                    a.v, Bf[kf][cb], Cacc[jb][cb], 0, 0, 0);
        }
    }

    float mx[2], rn[2];
    #pragma unroll
    for (int cb = 0; cb < 2; cb++) {
        float m0 = Cacc[0][cb][0];
        #pragma unroll
        for (int jb = 0; jb < 16; jb++)
            #pragma unroll
            for (int rg = 0; rg < 4; rg++) m0 = fmaxf(m0, Cacc[jb][cb][rg]);
        m0 = fmaxf(m0, __shfl_xor(m0, 16));
        m0 = fmaxf(m0, __shfl_xor(m0, 32));
        mx[cb] = m0; rn[cb] = 1.0f / m0;
    }

    __syncthreads();
    #pragma unroll
    for (int jb = 0; jb < 16; jb++)
        #pragma unroll
        for (int cb = 0; cb < 2; cb++) {
            int rsl = w * 32 + cb * 16 + ln15;
            #pragma unroll
            for (int rg = 0; rg < 4; rg++) {
                int j = jb * 16 + gl * 4 + rg;
                *(unsigned short*)(qt + ((j * 128 + rsl) << 1)) =
                    (unsigned short)f2bfu(Cacc[jb][cb][rg] * rn[cb]);
            }
        }
    __syncthreads();
    #pragma unroll
    for (int q = 0; q < 16; q++)
        *(uint4*)(SO + q * 4096 + t * 16) = *(const uint4*)(qt + q * 4096 + t * 16);
    if (lane < 16) {
        #pragma unroll
        for (int cb = 0; cb < 2; cb++) {
            int rsl = w * 32 + cb * 16 + lane;
            float se = *(const float*)(SE + 65536 + rsl * 4);
            *(float*)(SO + 65536 + rsl * 4) = se + sigma + __logf(mx[cb]);
        }
    }
}

__global__ __launch_bounds__(256, 1) void crf_combine2(
        const char* __restrict__ inb, char* __restrict__ outb) {
    __shared__ alignas(16) char qt[131072];
    __shared__ alignas(16) unsigned scr[4][512];
    __shared__ alignas(16) float efac[NTS];
    __shared__ float smax[4];
    const int t = threadIdx.x;
    combine_body(inb, outb, blockIdx.x >> 1, blockIdx.x & 1, qt, scr, efac, smax,
                 t, t & 63, t >> 6, (t & 63) >> 4, t & 15);
}

// ===========================================================================
// Fused chain + finalize + gold (round-9, proven): 16 serial matvecs.
// ===========================================================================
__global__ __launch_bounds__(512) void crf_chainfin16(
        const char* __restrict__ mats, const float* __restrict__ emit,
        const float* __restrict__ BOS, const int* __restrict__ y,
        const float* __restrict__ trans, const float* __restrict__ EOS,
        float* __restrict__ out) {
    __shared__ float red[8];
    __shared__ float smx[8];
    __shared__ alignas(16) float u[NTS];
    __shared__ float pu[NTS];
    const int t = threadIdx.x, lane = t & 63, wv = t >> 6;

    float s = 0.f;
    for (int i = t; i < TLEN - 1; i += 512) {
        int yi = y[i], yn = y[i + 1];
        s += trans[yi * NTS + yn] + emit[i * NTS + yi];
    }
    #pragma unroll
    for (int off = 32; off; off >>= 1) s += __shfl_down(s, off);
    if (lane == 0) red[wv] = s;

    float v0 = (t < NTS) ? (BOS[t] + emit[t]) : -INFINITY;
    float m = v0;
    #pragma unroll
    for (int off = 32; off; off >>= 1) m = fmaxf(m, __shfl_xor(m, off));
    if (lane == 0) smx[wv] = m;
    __syncthreads();
    const float m0 = fmaxf(fmaxf(smx[0], smx[1]), fmaxf(smx[2], smx[3]));
    float wreg = (t < NTS) ? __expf(v0 - m0) : 0.f;
    double W = (double)m0;
    __syncthreads();

    const int j2 = t & 255;
    const int hh = t >> 8;
    for (int c = 0; c < 16; ++c) {
        const char* M0 = mats + (size_t)(2 * c) * SLOT2;
        const char* M1 = M0 + SLOT2;
        float sv = -INFINITY;
        if (t < NTS) sv = *(const float*)(((t < 128) ? M0 : M1) + 65536 + (t & 127) * 4);
        m = sv;
        #pragma unroll
        for (int off = 32; off; off >>= 1) m = fmaxf(m, __shfl_xor(m, off));
        if (lane == 0) smx[wv] = m;
        __syncthreads();
        const float sigma = fmaxf(fmaxf(smx[0], smx[1]), fmaxf(smx[2], smx[3]));
        if (t < NTS) u[t] = __expf(sv - sigma) * wreg;
        __syncthreads();

        const char* Mh = hh ? M1 : M0;
        const uint4* rowp = (const uint4*)(Mh + (size_t)j2 * 256);
        const float* ub = u + hh * 128;
        float acc = 0.f;
        #pragma unroll
        for (int q = 0; q < 16; q++) acc += dot8(rowp[q], ub + q * 8);
        if (hh == 1) pu[j2] = acc;
        __syncthreads();
        float v = -INFINITY;
        if (t < NTS) v = acc + pu[t];
        m = v;
        #pragma unroll
        for (int off = 32; off; off >>= 1) m = fmaxf(m, __shfl_xor(m, off));
        if (lane == 0) smx[wv] = m;
        __syncthreads();
        const float mstep = fmaxf(fmaxf(smx[0], smx[1]), fmaxf(smx[2], smx[3]));
        W += (double)(sigma + __logf(mstep));
        if (t < NTS) wreg = v * (1.0f / mstep);
        __syncthreads();
    }

    float ssum = (t < NTS) ? wreg : 0.f;
    #pragma unroll
    for (int off = 32; off; off >>= 1) ssum += __shfl_down(ssum, off);
    if (lane == 0) smx[wv] = ssum;
    __syncthreads();
    if (t == 0) {
        float S = smx[0] + smx[1] + smx[2] + smx[3];
        float logZ = (float)(W + (double)__logf(S));
        float gold = 0.f;
        #pragma unroll
        for (int k = 0; k < 8; k++) gold += red[k];
        int y0 = y[0], yl = y[TLEN - 1];
        gold += BOS[y0] + EOS[yl] + emit[(TLEN - 1) * NTS + yl];
        out[0] = logZ - gold;
    }
}

// ===========================================================================
// Serial fallback (ws too small) — unchanged, verified
// ===========================================================================
__global__ __launch_bounds__(256) void crf_prep(const float* __restrict__ trans,
                                                __half2* __restrict__ Qp) {
    int j = threadIdx.x, p = blockIdx.x;
    float a = __expf(trans[(2 * p) * NTS + j]);
    float b = __expf(trans[(2 * p + 1) * NTS + j]);
    Qp[p * NTS + j] = __floats2half2_rn(a, b);
}

__global__ __launch_bounds__(512) void crf_forward(
        const float* __restrict__ emit, const float* __restrict__ BOS,
        const __half2* __restrict__ Qp_g, float* __restrict__ logZ_out) {
    __shared__ __half2 Qp[128 * NTS];
    __shared__ alignas(16) float w[NTS];
    __shared__ float part[2][NTS];
    __shared__ float ebuf[2][NTS];
    __shared__ float wavemax[8];
    const int t = threadIdx.x, j = t & 255, q = t >> 8, lane = t & 63, wv = t >> 6;
    for (int idx = t; idx < 128 * NTS; idx += 512) Qp[idx] = Qp_g[idx];
    float anew = -INFINITY;
    if (t < NTS) anew = BOS[t] + emit[t];
    float ml = anew;
    #pragma unroll
    for (int off = 32; off; off >>= 1) ml = fmaxf(ml, __shfl_down(ml, off));
    if (lane == 0) wavemax[wv] = ml;
    __syncthreads();
    float mstep = fmaxf(fmaxf(wavemax[0], wavemax[1]), fmaxf(wavemax[2], wavemax[3]));
    double Macc = (double)mstep;
    if (t < NTS) w[t] = __expf(anew - mstep);
    float epre = 0.f;
    if (q == 1) epre = emit[NTS + j];
    __syncthreads();
    for (int i = 1; i < TLEN; ++i) {
        if (q == 1) ebuf[i & 1][j] = epre;
        float acc = 0.f;
        const __half2* qptr = Qp + (q * 64) * NTS + j;
        const float2* wptr = (const float2*)(w + q * 128);
        #pragma unroll 16
        for (int kk = 0; kk < 64; ++kk) {
            __half2 qv = qptr[kk * NTS];
            float2 wv2 = wptr[kk];
            acc += __low2float(qv) * wv2.x + __high2float(qv) * wv2.y;
        }
        part[q][j] = acc;
        if (q == 1 && (i + 1) < TLEN) epre = emit[(i + 1) * NTS + j];
        __syncthreads();
        float an = 0.f;
        ml = -INFINITY;
        if (t < NTS) {
            float vv = part[0][t] + part[1][t];
            an = ebuf[i & 1][t] + __logf(vv);
            ml = an;
        }
        #pragma unroll
        for (int off = 32; off; off >>= 1) ml = fmaxf(ml, __shfl_down(ml, off));
        if (lane == 0 && wv < 4) wavemax[wv] = ml;
        __syncthreads();
        mstep = fmaxf(fmaxf(wavemax[0], wavemax[1]), fmaxf(wavemax[2], wavemax[3]));
        Macc += (double)mstep;
        if (t < NTS) w[t] = __expf(an - mstep);
        __syncthreads();
    }
    float s = (t < NTS) ? w[t] : 0.f;
    #pragma unroll
    for (int off = 32; off; off >>= 1) s += __shfl_down(s, off);
    if (lane == 0 && wv < 4) wavemax[wv] = s;
    __syncthreads();
    if (t == 0) {
        float tot = wavemax[0] + wavemax[1] + wavemax[2] + wavemax[3];
        logZ_out[0] = (float)(Macc + (double)__logf(tot));
    }
}

__global__ __launch_bounds__(512) void crf_gold(
        const float* __restrict__ emit, const int* __restrict__ y,
        const float* __restrict__ trans, const float* __restrict__ BOS,
        const float* __restrict__ EOS, const float* __restrict__ logZ_ws,
        float* __restrict__ out) {
    __shared__ float red[8];
    int t = threadIdx.x;
    float s = 0.f;
    for (int i = t; i < TLEN - 1; i += 512) {
        int yi = y[i], yn = y[i + 1];
        s += trans[yi * NTS + yn] + emit[i * NTS + yi];
    }
    #pragma unroll
    for (int off = 32; off; off >>= 1) s += __shfl_down(s, off);
    if ((t & 63) == 0) red[t >> 6] = s;
    __syncthreads();
    if (t == 0) {
        float tot = 0.f;
        #pragma unroll
        for (int k2 = 0; k2 < 8; ++k2) tot += red[k2];
        int y0 = y[0], yl = y[TLEN - 1];
        tot += BOS[y0] + EOS[yl] + emit[(TLEN - 1) * NTS + yl];
        out[0] = logZ_ws[0] - tot;
    }
}

// ===========================================================================
extern "C" void kernel_launch(void* const* d_in, const int* in_sizes, int n_in,
                              void* d_out, int out_size, void* d_ws, size_t ws_size,
                              hipStream_t stream) {
    const float* emit  = (const float*)d_in[0];
    const int*   y     = (const int*)d_in[1];
    const float* trans = (const float*)d_in[2];
    const float* BOS   = (const float*)d_in[3];
    const float* EOS   = (const float*)d_in[4];
    float* out = (float*)d_out;

    const size_t need = (size_t)(512 + 256) * SLOT2 + 256;
    if (ws_size >= need) {
        char* X = (char*)d_ws;                       // 512 half-slots
        char* Y = X + (size_t)512 * SLOT2;           // 256 half-slots

        crf_phase1<<<2 * NCH, 512, 0, stream>>>(emit, trans, X);
        crf_combine2<<<256, 256, 0, stream>>>(X, Y);   // 256 -> 128 matrices
        crf_combine2<<<128, 256, 0, stream>>>(Y, X);   // 128 -> 64
        crf_combine2<<<64, 256, 0, stream>>>(X, Y);    //  64 -> 32
        crf_combine2<<<32, 256, 0, stream>>>(Y, X);    //  32 -> 16
        crf_chainfin16<<<1, 512, 0, stream>>>(X, emit, BOS, y, trans, EOS, out);
    } else {
        __half2* Qp = (__half2*)d_ws;
        float* logZ = (float*)((char*)d_ws + 128 * NTS * sizeof(__half2));
        crf_prep<<<128, 256, 0, stream>>>(trans, Qp);
        crf_forward<<<1, 512, 0, stream>>>(emit, BOS, Qp, logZ);
        crf_gold<<<1, 512, 0, stream>>>(emit, y, trans, BOS, EOS, logZ, out);
    }
}

// Round 15
// 409.155 us; speedup vs baseline: 1.3444x; 1.1198x over previous
//
#include <hip/hip_runtime.h>
#include <hip/hip_fp16.h>

#define TLEN 8192
#define NTS  256
#define CLEN 32
#define NCH  256           // TLEN / CLEN
#define SLOT2 66048        // 256*128 bf16 (65536) + 128 f32 scales (512)

typedef __bf16 bf16x8 __attribute__((ext_vector_type(8)));
typedef float  f32x4  __attribute__((ext_vector_type(4)));
union U128 { uint4 u; bf16x8 v; };
union U64  { uint2 u; long l; };

__device__ __forceinline__ unsigned f2bfu(float x) {
    unsigned u = __float_as_uint(x);
    return (u + 0x7fffu + ((u >> 16) & 1u)) >> 16;
}
__device__ __forceinline__ unsigned pk2(float lo, float hi) {
    return f2bfu(lo) | (f2bfu(hi) << 16);
}
__device__ __forceinline__ float bf2f(unsigned short h) {
    return __uint_as_float(((unsigned)h) << 16);
}
__device__ __forceinline__ unsigned pk4bf8(float a, float b, float c, float d) {
    int r = __builtin_amdgcn_cvt_pk_bf8_f32(a, b, 0, false);
    r = __builtin_amdgcn_cvt_pk_bf8_f32(c, d, r, true);
    return (unsigned)r;
}
__device__ __forceinline__ float dot8(uint4 a, const float* uq) {
    return bf2f((unsigned short)(a.x & 0xffffu)) * uq[0]
         + bf2f((unsigned short)(a.x >> 16))     * uq[1]
         + bf2f((unsigned short)(a.y & 0xffffu)) * uq[2]
         + bf2f((unsigned short)(a.y >> 16))     * uq[3]
         + bf2f((unsigned short)(a.z & 0xffffu)) * uq[4]
         + bf2f((unsigned short)(a.z >> 16))     * uq[5]
         + bf2f((unsigned short)(a.w & 0xffffu)) * uq[6]
         + bf2f((unsigned short)(a.w >> 16))     * uq[7];
}

// ===========================================================================
// Phase 1 (fp8): ROUND-9 PROVEN GEOMETRY — block = (chunk c, col-half h),
// 256 thr = 4 waves, wave owns 32 columns, 2 blocks/CU. Q in LDS as bf8
// e5m2 (64 KiB). Output LINEAR bf16 + f32 column log scales. 224 us.
// ===========================================================================
__global__ __launch_bounds__(256, 2) void crf_phase1(
        const float* __restrict__ emit, const float* __restrict__ trans,
        char* __restrict__ outX) {
    __shared__ alignas(16) char qt8[65536];      // QT[j][k] bf8, granule-rotated
    __shared__ alignas(16) char scr[4][1280];    // exchange: 32 cols x 40 B/wave
    __shared__ alignas(16) float eld[2][NTS];    // exp(emit row), dbuf

    const int t    = threadIdx.x;
    const int lane = t & 63;
    const int w    = t >> 6;              // 0..3
    const int gl   = lane >> 4;           // 0..3
    const int ln15 = lane & 15;
    const int c    = blockIdx.x >> 1;
    const int h    = blockIdx.x & 1;
    const int istart = (c == 0) ? 1 : CLEN * c;
    const int iend   = CLEN * c + CLEN;

    // ---- stage QT[j][k] = exp(trans[k][j]) as bf8, rotated granules ------
    {
        const int ln = t & 15;
        for (int gk = 0; gk < 32; gk++) {
            float v[8];
            #pragma unroll
            for (int e = 0; e < 8; e++) v[e] = __expf(trans[(gk * 8 + e) * NTS + t]);
            uint2 u;
            u.x = pk4bf8(v[0], v[1], v[2], v[3]);
            u.y = pk4bf8(v[4], v[5], v[6], v[7]);
            const int p = (gk + 4 * ln + (ln >> 2)) & 31;
            *(uint2*)(qt8 + t * 256 + p * 8) = u;
        }
    }
    eld[istart & 1][t] = __expf(emit[istart * NTS + t]);

    int aoff[8];
    #pragma unroll
    for (int kf = 0; kf < 8; kf++) {
        const int p = (4 * kf + gl + 4 * ln15 + (ln15 >> 2)) & 31;
        aoff[kf] = ln15 * 256 + p * 8;
    }

    // ---- B := Identity columns (bf8 1.0 = 0x3C), rs := 0 -----------------
    uint2 Bf[8][2];
    #pragma unroll
    for (int kf = 0; kf < 8; kf++)
        #pragma unroll
        for (int cb = 0; cb < 2; cb++) {
            uint2 bu; bu.x = 0u; bu.y = 0u;
            const int r_glob = 128 * h + 32 * w + cb * 16 + ln15;
            if ((r_glob >> 3) == kf * 4 + gl) {
                const int e = r_glob & 7;
                if (e < 4) bu.x = 0x3Cu << (8 * e);
                else       bu.y = 0x3Cu << (8 * (e - 4));
            }
            Bf[kf][cb] = bu;
        }
    float rs[2] = {0.f, 0.f};
    __syncthreads();

    char* const mysc = &scr[w][0];
    for (int i = istart; i < iend; ++i) {
        float enext = 0.f;
        if (i + 1 < iend) enext = emit[(i + 1) * NTS + t];

        // ---- C = QT * B (bf8 MFMA) ---------------------------------------
        f32x4 Cacc[16][2];
        #pragma unroll
        for (int jb = 0; jb < 16; jb++)
            #pragma unroll
            for (int cb = 0; cb < 2; cb++) Cacc[jb][cb] = f32x4{0.f, 0.f, 0.f, 0.f};

        #pragma unroll
        for (int jb = 0; jb < 16; jb++) {
            #pragma unroll
            for (int kf = 0; kf < 8; kf++) {
                U64 a; a.u = *(const uint2*)(qt8 + (aoff[kf] + jb * 4096));
                #pragma unroll
                for (int cb = 0; cb < 2; cb++) {
                    U64 b; b.u = Bf[kf][cb];
                    Cacc[jb][cb] = __builtin_amdgcn_mfma_f32_16x16x32_bf8_bf8(
                        a.l, b.l, Cacc[jb][cb], 0, 0, 0);
                }
            }
        }

        // ---- scale rows j by exp(emit[i][j]) ------------------------------
        #pragma unroll
        for (int jb = 0; jb < 16; jb++) {
            float4 ev = *(const float4*)&eld[i & 1][jb * 16 + gl * 4];
            #pragma unroll
            for (int cb = 0; cb < 2; cb++) {
                Cacc[jb][cb][0] *= ev.x; Cacc[jb][cb][1] *= ev.y;
                Cacc[jb][cb][2] *= ev.z; Cacc[jb][cb][3] *= ev.w;
            }
        }
        // ---- per-column max + renormalize ---------------------------------
        float rn[2];
        #pragma unroll
        for (int cb = 0; cb < 2; cb++) {
            float m0 = Cacc[0][cb][0];
            #pragma unroll
            for (int jb = 0; jb < 16; jb++)
                #pragma unroll
                for (int rg = 0; rg < 4; rg++) m0 = fmaxf(m0, Cacc[jb][cb][rg]);
            m0 = fmaxf(m0, __shfl_xor(m0, 16));
            m0 = fmaxf(m0, __shfl_xor(m0, 32));
            rn[cb] = 1.0f / m0;
            rs[cb] += __logf(m0);
        }

        if (i == iend - 1) {
            // ---- coalesced write: scatter into qt8 (dead), then copy out ---
            __syncthreads();              // all waves done reading qt8 (MFMA)
            #pragma unroll
            for (int jb = 0; jb < 16; jb++)
                #pragma unroll
                for (int cb = 0; cb < 2; cb++) {
                    int rsl = w * 32 + cb * 16 + ln15;
                    #pragma unroll
                    for (int rg = 0; rg < 4; rg++) {
                        int j = jb * 16 + gl * 4 + rg;
                        *(unsigned short*)(qt8 + ((j * 128 + rsl) << 1)) =
                            (unsigned short)f2bfu(Cacc[jb][cb][rg] * rn[cb]);
                    }
                }
            __syncthreads();
            char* SO = outX + (size_t)(2 * c + h) * SLOT2;
            #pragma unroll
            for (int q = 0; q < 16; q++)
                *(uint4*)(SO + q * 4096 + t * 16) =
                    *(const uint4*)(qt8 + q * 4096 + t * 16);
            if (lane < 16) {
                #pragma unroll
                for (int cb = 0; cb < 2; cb++) {
                    int rsl = w * 32 + cb * 16 + lane;
                    *(float*)(SO + 65536 + rsl * 4) = rs[cb];
                }
            }
        } else {
            // ---- C -> next B (bf8) via intra-wave LDS exchange -------------
            #pragma unroll
            for (int kf = 0; kf < 8; kf++) {
                #pragma unroll
                for (int jbb = 0; jbb < 2; jbb++) {
                    const int jb = 2 * kf + jbb;
                    #pragma unroll
                    for (int cb = 0; cb < 2; cb++) {
                        const int col = cb * 16 + ln15;
                        unsigned pk = pk4bf8(Cacc[jb][cb][0] * rn[cb],
                                             Cacc[jb][cb][1] * rn[cb],
                                             Cacc[jb][cb][2] * rn[cb],
                                             Cacc[jb][cb][3] * rn[cb]);
                        *(unsigned*)(mysc + col * 40 + jbb * 16 + gl * 4) = pk;
                    }
                }
                asm volatile("s_waitcnt lgkmcnt(0)" ::: "memory");
                __builtin_amdgcn_sched_barrier(0);
                #pragma unroll
                for (int cb = 0; cb < 2; cb++) {
                    const int col = cb * 16 + ln15;
                    Bf[kf][cb] = *(const uint2*)(mysc + col * 40 + gl * 8);
                }
                asm volatile("s_waitcnt lgkmcnt(0)" ::: "memory");
                __builtin_amdgcn_sched_barrier(0);
            }
            eld[(i + 1) & 1][t] = __expf(enext);
            __syncthreads();
        }
    }
}

// ===========================================================================
// Binary-combine body (round-9, proven): out (p,h) = Later(2p+1) x
// Earlier(2p), columns [128h,128h+128), linear storage.
// ===========================================================================
__device__ __forceinline__ void combine_body(
        const char* __restrict__ inb, char* __restrict__ outb,
        int p, int h, char* qt, unsigned (*scr)[512],
        float* efac, float* smax,
        int t, int lane, int w, int gl, int ln15) {
    const char* SL0 = inb + (size_t)(4 * p + 2) * SLOT2;
    const char* SL1 = inb + (size_t)(4 * p + 3) * SLOT2;
    const char* SE  = inb + (size_t)(4 * p + h) * SLOT2;
    char* SO = outb + (size_t)(2 * p + h) * SLOT2;

    float sv = *(const float*)(((t < 128) ? SL0 : SL1) + 65536 + (t & 127) * 4);
    float m = sv;
    #pragma unroll
    for (int off = 32; off; off >>= 1) m = fmaxf(m, __shfl_xor(m, off));
    if (lane == 0) smax[w] = m;
    __syncthreads();
    const float sigma = fmaxf(fmaxf(smax[0], smax[1]), fmaxf(smax[2], smax[3]));
    efac[t] = __expf(sv - sigma);
    __syncthreads();

    for (int it = 0; it < 32; it++) {
        int off = it * 2048 + t * 8;
        int j = off >> 8, k = off & 255;
        const char* src = (k < 128) ? (SL0 + (size_t)(j * 128 + k) * 2)
                                    : (SL1 + (size_t)(j * 128 + (k - 128)) * 2);
        uint4 d = *(const uint4*)src;
        float4 e0 = *(const float4*)&efac[k];
        float4 e1 = *(const float4*)&efac[k + 4];
        float ef[8] = {e0.x, e0.y, e0.z, e0.w, e1.x, e1.y, e1.z, e1.w};
        unsigned wds[4] = {d.x, d.y, d.z, d.w};
        unsigned outw[4];
        #pragma unroll
        for (int wi = 0; wi < 4; wi++) {
            float lo = bf2f((unsigned short)(wds[wi] & 0xffffu)) * ef[2 * wi];
            float hi = bf2f((unsigned short)(wds[wi] >> 16)) * ef[2 * wi + 1];
            outw[wi] = pk2(lo, hi);
        }
        uint4 o; o.x = outw[0]; o.y = outw[1]; o.z = outw[2]; o.w = outw[3];
        *(uint4*)(qt + ((j * 512 + k * 2) ^ ((j & 7) << 4))) = o;
    }

    bf16x8 Bf[8][2];
    #pragma unroll
    for (int kf = 0; kf < 8; kf++) {
        #pragma unroll
        for (int p2 = 0; p2 < 2; p2++) {
            int kk = p2 * 16 + (lane >> 2);
            uint4 d = *(const uint4*)(SE + (size_t)(32 * kf + kk) * 256
                                      + w * 64 + (lane & 3) * 16);
            *(uint4*)((char*)&scr[w][0] + kk * 64 + (lane & 3) * 16) = d;
        }
        asm volatile("s_waitcnt lgkmcnt(0)" ::: "memory");
        __builtin_amdgcn_sched_barrier(0);
        #pragma unroll
        for (int cb = 0; cb < 2; cb++) {
            unsigned wd[4] = {0u, 0u, 0u, 0u};
            #pragma unroll
            for (int e = 0; e < 8; e++) {
                int kloc = gl * 8 + e;
                unsigned short hh = *(const unsigned short*)
                    ((const char*)&scr[w][0] + kloc * 64 + (cb * 16 + ln15) * 2);
                wd[e >> 1] |= ((unsigned)hh) << (16 * (e & 1));
            }
            U128 q; q.u.x = wd[0]; q.u.y = wd[1]; q.u.z = wd[2]; q.u.w = wd[3];
            Bf[kf][cb] = q.v;
        }
        asm volatile("s_waitcnt lgkmcnt(0)" ::: "memory");
        __builtin_amdgcn_sched_barrier(0);
    }
    __syncthreads();

    f32x4 Cacc[16][2];
    #pragma unroll
    for (int jb = 0; jb < 16; jb++)
        #pragma unroll
        for (int cb = 0; cb < 2; cb++) Cacc[jb][cb] = f32x4{0.f, 0.f, 0.f, 0.f};
    const int aswz = (lane & 7) << 4;
    #pragma unroll
    for (int jb = 0; jb < 16; jb++) {
        const int abase = (jb * 16 + ln15) * 512 + gl * 16;
        #pragma unroll
        for (int kf = 0; kf < 8; kf++) {
            U128 a; a.u = *(const uint4*)(qt + ((abase + kf * 64) ^ aswz));
            #pragma unroll
            for (int cb = 0; cb < 2; cb++)
                Cacc[jb][cb] = __builtin_amdgcn_mfma_f32_16x16x32_bf16(
                    a.v, Bf[kf][cb], Cacc[jb][cb], 0, 0, 0);
        }
    }

    float mx[2], rn[2];
    #pragma unroll
    for (int cb = 0; cb < 2; cb++) {
        float m0 = Cacc[0][cb][0];
        #pragma unroll
        for (int jb = 0; jb < 16; jb++)
            #pragma unroll
            for (int rg = 0; rg < 4; rg++) m0 = fmaxf(m0, Cacc[jb][cb][rg]);
        m0 = fmaxf(m0, __shfl_xor(m0, 16));
        m0 = fmaxf(m0, __shfl_xor(m0, 32));
        mx[cb] = m0; rn[cb] = 1.0f / m0;
    }

    __syncthreads();
    #pragma unroll
    for (int jb = 0; jb < 16; jb++)
        #pragma unroll
        for (int cb = 0; cb < 2; cb++) {
            int rsl = w * 32 + cb * 16 + ln15;
            #pragma unroll
            for (int rg = 0; rg < 4; rg++) {
                int j = jb * 16 + gl * 4 + rg;
                *(unsigned short*)(qt + ((j * 128 + rsl) << 1)) =
                    (unsigned short)f2bfu(Cacc[jb][cb][rg] * rn[cb]);
            }
        }
    __syncthreads();
    #pragma unroll
    for (int q = 0; q < 16; q++)
        *(uint4*)(SO + q * 4096 + t * 16) = *(const uint4*)(qt + q * 4096 + t * 16);
    if (lane < 16) {
        #pragma unroll
        for (int cb = 0; cb < 2; cb++) {
            int rsl = w * 32 + cb * 16 + lane;
            float se = *(const float*)(SE + 65536 + rsl * 4);
            *(float*)(SO + 65536 + rsl * 4) = se + sigma + __logf(mx[cb]);
        }
    }
}

__global__ __launch_bounds__(256, 1) void crf_combine2(
        const char* __restrict__ inb, char* __restrict__ outb) {
    __shared__ alignas(16) char qt[131072];
    __shared__ alignas(16) unsigned scr[4][512];
    __shared__ alignas(16) float efac[NTS];
    __shared__ float smax[4];
    const int t = threadIdx.x;
    combine_body(inb, outb, blockIdx.x >> 1, blockIdx.x & 1, qt, scr, efac, smax,
                 t, t & 63, t >> 6, (t & 63) >> 4, t & 15);
}

// ===========================================================================
// Fused chain + finalize + gold: 16 serial matvecs. NEW: row loads issued
// as one clustered burst at step top (before sigma/u phase) into registers
// — raises in-flight bytes ~8x on the latency-bound matrix read.
// ===========================================================================
__global__ __launch_bounds__(512) void crf_chainfin16(
        const char* __restrict__ mats, const float* __restrict__ emit,
        const float* __restrict__ BOS, const int* __restrict__ y,
        const float* __restrict__ trans, const float* __restrict__ EOS,
        float* __restrict__ out) {
    __shared__ float red[8];
    __shared__ float smx[8];
    __shared__ alignas(16) float u[NTS];
    __shared__ float pu[NTS];
    const int t = threadIdx.x, lane = t & 63, wv = t >> 6;

    float s = 0.f;
    for (int i = t; i < TLEN - 1; i += 512) {
        int yi = y[i], yn = y[i + 1];
        s += trans[yi * NTS + yn] + emit[i * NTS + yi];
    }
    #pragma unroll
    for (int off = 32; off; off >>= 1) s += __shfl_down(s, off);
    if (lane == 0) red[wv] = s;

    float v0 = (t < NTS) ? (BOS[t] + emit[t]) : -INFINITY;
    float m = v0;
    #pragma unroll
    for (int off = 32; off; off >>= 1) m = fmaxf(m, __shfl_xor(m, off));
    if (lane == 0) smx[wv] = m;
    __syncthreads();
    const float m0 = fmaxf(fmaxf(smx[0], smx[1]), fmaxf(smx[2], smx[3]));
    float wreg = (t < NTS) ? __expf(v0 - m0) : 0.f;
    double W = (double)m0;
    __syncthreads();

    const int j2 = t & 255;
    const int hh = t >> 8;
    for (int c = 0; c < 16; ++c) {
        const char* M0 = mats + (size_t)(2 * c) * SLOT2;
        const char* M1 = M0 + SLOT2;

        // ---- clustered row-load burst (fires before the u-phase) ----------
        const char* Mh = hh ? M1 : M0;
        const uint4* rowp = (const uint4*)(Mh + (size_t)j2 * 256);
        uint4 regs[16];
        #pragma unroll
        for (int q = 0; q < 16; q++) regs[q] = rowp[q];

        // ---- sigma + u (loads complete underneath) ------------------------
        float sv = -INFINITY;
        if (t < NTS) sv = *(const float*)(((t < 128) ? M0 : M1) + 65536 + (t & 127) * 4);
        m = sv;
        #pragma unroll
        for (int off = 32; off; off >>= 1) m = fmaxf(m, __shfl_xor(m, off));
        if (lane == 0) smx[wv] = m;
        __syncthreads();
        const float sigma = fmaxf(fmaxf(smx[0], smx[1]), fmaxf(smx[2], smx[3]));
        if (t < NTS) u[t] = __expf(sv - sigma) * wreg;
        __syncthreads();

        // ---- dot from registers -------------------------------------------
        const float* ub = u + hh * 128;
        float acc = 0.f;
        #pragma unroll
        for (int q = 0; q < 16; q++) acc += dot8(regs[q], ub + q * 8);
        if (hh == 1) pu[j2] = acc;
        __syncthreads();
        float v = -INFINITY;
        if (t < NTS) v = acc + pu[t];
        m = v;
        #pragma unroll
        for (int off = 32; off; off >>= 1) m = fmaxf(m, __shfl_xor(m, off));
        if (lane == 0) smx[wv] = m;
        __syncthreads();
        const float mstep = fmaxf(fmaxf(smx[0], smx[1]), fmaxf(smx[2], smx[3]));
        W += (double)(sigma + __logf(mstep));
        if (t < NTS) wreg = v * (1.0f / mstep);
        __syncthreads();
    }

    float ssum = (t < NTS) ? wreg : 0.f;
    #pragma unroll
    for (int off = 32; off; off >>= 1) ssum += __shfl_down(ssum, off);
    if (lane == 0) smx[wv] = ssum;
    __syncthreads();
    if (t == 0) {
        float S = smx[0] + smx[1] + smx[2] + smx[3];
        float logZ = (float)(W + (double)__logf(S));
        float gold = 0.f;
        #pragma unroll
        for (int k = 0; k < 8; k++) gold += red[k];
        int y0 = y[0], yl = y[TLEN - 1];
        gold += BOS[y0] + EOS[yl] + emit[(TLEN - 1) * NTS + yl];
        out[0] = logZ - gold;
    }
}

// ===========================================================================
// Serial fallback (ws too small) — unchanged, verified
// ===========================================================================
__global__ __launch_bounds__(256) void crf_prep(const float* __restrict__ trans,
                                                __half2* __restrict__ Qp) {
    int j = threadIdx.x, p = blockIdx.x;
    float a = __expf(trans[(2 * p) * NTS + j]);
    float b = __expf(trans[(2 * p + 1) * NTS + j]);
    Qp[p * NTS + j] = __floats2half2_rn(a, b);
}

__global__ __launch_bounds__(512) void crf_forward(
        const float* __restrict__ emit, const float* __restrict__ BOS,
        const __half2* __restrict__ Qp_g, float* __restrict__ logZ_out) {
    __shared__ __half2 Qp[128 * NTS];
    __shared__ alignas(16) float w[NTS];
    __shared__ float part[2][NTS];
    __shared__ float ebuf[2][NTS];
    __shared__ float wavemax[8];
    const int t = threadIdx.x, j = t & 255, q = t >> 8, lane = t & 63, wv = t >> 6;
    for (int idx = t; idx < 128 * NTS; idx += 512) Qp[idx] = Qp_g[idx];
    float anew = -INFINITY;
    if (t < NTS) anew = BOS[t] + emit[t];
    float ml = anew;
    #pragma unroll
    for (int off = 32; off; off >>= 1) ml = fmaxf(ml, __shfl_down(ml, off));
    if (lane == 0) wavemax[wv] = ml;
    __syncthreads();
    float mstep = fmaxf(fmaxf(wavemax[0], wavemax[1]), fmaxf(wavemax[2], wavemax[3]));
    double Macc = (double)mstep;
    if (t < NTS) w[t] = __expf(anew - mstep);
    float epre = 0.f;
    if (q == 1) epre = emit[NTS + j];
    __syncthreads();
    for (int i = 1; i < TLEN; ++i) {
        if (q == 1) ebuf[i & 1][j] = epre;
        float acc = 0.f;
        const __half2* qptr = Qp + (q * 64) * NTS + j;
        const float2* wptr = (const float2*)(w + q * 128);
        #pragma unroll 16
        for (int kk = 0; kk < 64; ++kk) {
            __half2 qv = qptr[kk * NTS];
            float2 wv2 = wptr[kk];
            acc += __low2float(qv) * wv2.x + __high2float(qv) * wv2.y;
        }
        part[q][j] = acc;
        if (q == 1 && (i + 1) < TLEN) epre = emit[(i + 1) * NTS + j];
        __syncthreads();
        float an = 0.f;
        ml = -INFINITY;
        if (t < NTS) {
            float vv = part[0][t] + part[1][t];
            an = ebuf[i & 1][t] + __logf(vv);
            ml = an;
        }
        #pragma unroll
        for (int off = 32; off; off >>= 1) ml = fmaxf(ml, __shfl_down(ml, off));
        if (lane == 0 && wv < 4) wavemax[wv] = ml;
        __syncthreads();
        mstep = fmaxf(fmaxf(wavemax[0], wavemax[1]), fmaxf(wavemax[2], wavemax[3]));
        Macc += (double)mstep;
        if (t < NTS) w[t] = __expf(an - mstep);
        __syncthreads();
    }
    float s = (t < NTS) ? w[t] : 0.f;
    #pragma unroll
    for (int off = 32; off; off >>= 1) s += __shfl_down(s, off);
    if (lane == 0 && wv < 4) wavemax[wv] = s;
    __syncthreads();
    if (t == 0) {
        float tot = wavemax[0] + wavemax[1] + wavemax[2] + wavemax[3];
        logZ_out[0] = (float)(Macc + (double)__logf(tot));
    }
}

__global__ __launch_bounds__(512) void crf_gold(
        const float* __restrict__ emit, const int* __restrict__ y,
        const float* __restrict__ trans, const float* __restrict__ BOS,
        const float* __restrict__ EOS, const float* __restrict__ logZ_ws,
        float* __restrict__ out) {
    __shared__ float red[8];
    int t = threadIdx.x;
    float s = 0.f;
    for (int i = t; i < TLEN - 1; i += 512) {
        int yi = y[i], yn = y[i + 1];
        s += trans[yi * NTS + yn] + emit[i * NTS + yi];
    }
    #pragma unroll
    for (int off = 32; off; off >>= 1) s += __shfl_down(s, off);
    if ((t & 63) == 0) red[t >> 6] = s;
    __syncthreads();
    if (t == 0) {
        float tot = 0.f;
        #pragma unroll
        for (int k2 = 0; k2 < 8; ++k2) tot += red[k2];
        int y0 = y[0], yl = y[TLEN - 1];
        tot += BOS[y0] + EOS[yl] + emit[(TLEN - 1) * NTS + yl];
        out[0] = logZ_ws[0] - tot;
    }
}

// ===========================================================================
extern "C" void kernel_launch(void* const* d_in, const int* in_sizes, int n_in,
                              void* d_out, int out_size, void* d_ws, size_t ws_size,
                              hipStream_t stream) {
    const float* emit  = (const float*)d_in[0];
    const int*   y     = (const int*)d_in[1];
    const float* trans = (const float*)d_in[2];
    const float* BOS   = (const float*)d_in[3];
    const float* EOS   = (const float*)d_in[4];
    float* out = (float*)d_out;

    const size_t need = (size_t)(512 + 256) * SLOT2 + 256;
    if (ws_size >= need) {
        char* X = (char*)d_ws;                       // 512 half-slots
        char* Y = X + (size_t)512 * SLOT2;           // 256 half-slots

        crf_phase1<<<2 * NCH, 256, 0, stream>>>(emit, trans, X);
        crf_combine2<<<256, 256, 0, stream>>>(X, Y);   // 256 -> 128 matrices
        crf_combine2<<<128, 256, 0, stream>>>(Y, X);   // 128 -> 64
        crf_combine2<<<64, 256, 0, stream>>>(X, Y);    //  64 -> 32
        crf_combine2<<<32, 256, 0, stream>>>(Y, X);    //  32 -> 16
        crf_chainfin16<<<1, 512, 0, stream>>>(X, emit, BOS, y, trans, EOS, out);
    } else {
        __half2* Qp = (__half2*)d_ws;
        float* logZ = (float*)((char*)d_ws + 128 * NTS * sizeof(__half2));
        crf_prep<<<128, 256, 0, stream>>>(trans, Qp);
        crf_forward<<<1, 512, 0, stream>>>(emit, BOS, Qp, logZ);
        crf_gold<<<1, 512, 0, stream>>>(emit, y, trans, BOS, EOS, logZ, out);
    }
}

// Round 16
// 394.049 us; speedup vs baseline: 1.3960x; 1.0383x over previous
//
#include <hip/hip_runtime.h>
#include <hip/hip_fp16.h>

#define TLEN 8192
#define NTS  256
#define CLEN 32
#define NCH  256           // TLEN / CLEN
#define SLOT2 66048        // 256*128 bf16 (65536) + 128 f32 scales (512)

typedef __bf16 bf16x8 __attribute__((ext_vector_type(8)));
typedef float  f32x4  __attribute__((ext_vector_type(4)));
typedef int    v8i    __attribute__((ext_vector_type(8)));
union U128 { uint4 u; bf16x8 v; };
union U64  { uint2 u; long l; };
union U256 { unsigned u[8]; v8i v; };

__device__ __forceinline__ unsigned f2bfu(float x) {
    unsigned u = __float_as_uint(x);
    return (u + 0x7fffu + ((u >> 16) & 1u)) >> 16;
}
__device__ __forceinline__ unsigned pk2(float lo, float hi) {
    return f2bfu(lo) | (f2bfu(hi) << 16);
}
__device__ __forceinline__ float bf2f(unsigned short h) {
    return __uint_as_float(((unsigned)h) << 16);
}
__device__ __forceinline__ unsigned pk4bf8(float a, float b, float c, float d) {
    int r = __builtin_amdgcn_cvt_pk_bf8_f32(a, b, 0, false);
    r = __builtin_amdgcn_cvt_pk_bf8_f32(c, d, r, true);
    return (unsigned)r;
}
__device__ __forceinline__ float dot8(uint4 a, const float* uq) {
    return bf2f((unsigned short)(a.x & 0xffffu)) * uq[0]
         + bf2f((unsigned short)(a.x >> 16))     * uq[1]
         + bf2f((unsigned short)(a.y & 0xffffu)) * uq[2]
         + bf2f((unsigned short)(a.y >> 16))     * uq[3]
         + bf2f((unsigned short)(a.z & 0xffffu)) * uq[4]
         + bf2f((unsigned short)(a.z >> 16))     * uq[5]
         + bf2f((unsigned short)(a.w & 0xffffu)) * uq[6]
         + bf2f((unsigned short)(a.w >> 16))     * uq[7];
}

// ===========================================================================
// Phase 1 (MX-fp8 K=128): round-9 geometry (256 thr, 4 waves, 32 cols/wave,
// 2 blocks/CU) but MFMA = mfma_scale_f32_16x16x128_f8f6f4 (bf8, unit scale)
// -> 64 MFMA/step/wave instead of 256. Exchange: 4 rounds (kf2 x cb), 2KB/wave
// scratch, 16B-block XOR swizzle. A-reads and C/D layout unchanged.
// ===========================================================================
__global__ __launch_bounds__(256, 2) void crf_phase1(
        const float* __restrict__ emit, const float* __restrict__ trans,
        char* __restrict__ outX) {
    __shared__ alignas(16) char qt8[65536];      // QT[j][k] bf8, granule-rotated
    __shared__ alignas(16) char scr[4][2048];    // exchange: 16 rows x 128 B/wave
    __shared__ alignas(16) float eld[2][NTS];    // exp(emit row), dbuf

    const int t    = threadIdx.x;
    const int lane = t & 63;
    const int w    = t >> 6;              // 0..3
    const int gl   = lane >> 4;           // 0..3
    const int ln15 = lane & 15;
    const int c    = blockIdx.x >> 1;
    const int h    = blockIdx.x & 1;
    const int istart = (c == 0) ? 1 : CLEN * c;
    const int iend   = CLEN * c + CLEN;

    // ---- stage QT[j][k] = exp(trans[k][j]) as bf8, rotated granules ------
    {
        const int ln = t & 15;
        for (int gk = 0; gk < 32; gk++) {
            float v[8];
            #pragma unroll
            for (int e = 0; e < 8; e++) v[e] = __expf(trans[(gk * 8 + e) * NTS + t]);
            uint2 u;
            u.x = pk4bf8(v[0], v[1], v[2], v[3]);
            u.y = pk4bf8(v[4], v[5], v[6], v[7]);
            const int p = (gk + 4 * ln + (ln >> 2)) & 31;
            *(uint2*)(qt8 + t * 256 + p * 8) = u;
        }
    }
    eld[istart & 1][t] = __expf(emit[istart * NTS + t]);

    // ---- A-read offsets: granule gk = kf2*16 + gl*4 + q ------------------
    int abase[2][4];
    #pragma unroll
    for (int kf2 = 0; kf2 < 2; kf2++)
        #pragma unroll
        for (int q = 0; q < 4; q++) {
            const int gk = kf2 * 16 + gl * 4 + q;
            const int p = (gk + 4 * ln15 + (ln15 >> 2)) & 31;
            abase[kf2][q] = ln15 * 256 + p * 8;
        }

    // ---- B := Identity columns (bf8 1.0 = 0x3C), rs := 0 -----------------
    v8i Bf[2][2];
    #pragma unroll
    for (int kf2 = 0; kf2 < 2; kf2++)
        #pragma unroll
        for (int cb = 0; cb < 2; cb++) {
            U256 b;
            #pragma unroll
            for (int q = 0; q < 8; q++) b.u[q] = 0u;
            const int r_glob = 128 * h + 32 * w + cb * 16 + ln15;
            const int e = r_glob - kf2 * 128 - gl * 32;
            if (e >= 0 && e < 32) b.u[e >> 2] = 0x3Cu << (8 * (e & 3));
            Bf[kf2][cb] = b.v;
        }
    float rs[2] = {0.f, 0.f};
    const int swz = (ln15 & 7) << 4;
    __syncthreads();

    char* const mysc = &scr[w][0];
    for (int i = istart; i < iend; ++i) {
        float enext = 0.f;
        if (i + 1 < iend) enext = emit[(i + 1) * NTS + t];

        // ---- C = QT * B (MX bf8 MFMA, K=128, unit scales) -----------------
        f32x4 Cacc[16][2];
        #pragma unroll
        for (int jb = 0; jb < 16; jb++)
            #pragma unroll
            for (int cb = 0; cb < 2; cb++) Cacc[jb][cb] = f32x4{0.f, 0.f, 0.f, 0.f};

        #pragma unroll
        for (int jb = 0; jb < 16; jb++) {
            #pragma unroll
            for (int kf2 = 0; kf2 < 2; kf2++) {
                U256 a;
                #pragma unroll
                for (int q = 0; q < 4; q++) {
                    uint2 g = *(const uint2*)(qt8 + jb * 4096 + abase[kf2][q]);
                    a.u[2 * q] = g.x; a.u[2 * q + 1] = g.y;
                }
                #pragma unroll
                for (int cb = 0; cb < 2; cb++)
                    Cacc[jb][cb] = __builtin_amdgcn_mfma_scale_f32_16x16x128_f8f6f4(
                        a.v, Bf[kf2][cb], Cacc[jb][cb],
                        1, 1,            // cbsz=bf8(e5m2), blgp=bf8(e5m2)
                        0, 0x7F,         // opsel_a, scale_a (e8m0 127 = x1)
                        0, 0x7F);        // opsel_b, scale_b
            }
        }

        // ---- scale rows j by exp(emit[i][j]) ------------------------------
        #pragma unroll
        for (int jb = 0; jb < 16; jb++) {
            float4 ev = *(const float4*)&eld[i & 1][jb * 16 + gl * 4];
            #pragma unroll
            for (int cb = 0; cb < 2; cb++) {
                Cacc[jb][cb][0] *= ev.x; Cacc[jb][cb][1] *= ev.y;
                Cacc[jb][cb][2] *= ev.z; Cacc[jb][cb][3] *= ev.w;
            }
        }
        // ---- per-column max + renormalize ---------------------------------
        float rn[2];
        #pragma unroll
        for (int cb = 0; cb < 2; cb++) {
            float m0 = Cacc[0][cb][0];
            #pragma unroll
            for (int jb = 0; jb < 16; jb++)
                #pragma unroll
                for (int rg = 0; rg < 4; rg++) m0 = fmaxf(m0, Cacc[jb][cb][rg]);
            m0 = fmaxf(m0, __shfl_xor(m0, 16));
            m0 = fmaxf(m0, __shfl_xor(m0, 32));
            rn[cb] = 1.0f / m0;
            rs[cb] += __logf(m0);
        }

        if (i == iend - 1) {
            // ---- coalesced write: scatter into qt8 (dead), then copy out ---
            __syncthreads();              // all waves done reading qt8 (MFMA)
            #pragma unroll
            for (int jb = 0; jb < 16; jb++)
                #pragma unroll
                for (int cb = 0; cb < 2; cb++) {
                    int rsl = w * 32 + cb * 16 + ln15;
                    #pragma unroll
                    for (int rg = 0; rg < 4; rg++) {
                        int j = jb * 16 + gl * 4 + rg;
                        *(unsigned short*)(qt8 + ((j * 128 + rsl) << 1)) =
                            (unsigned short)f2bfu(Cacc[jb][cb][rg] * rn[cb]);
                    }
                }
            __syncthreads();
            char* SO = outX + (size_t)(2 * c + h) * SLOT2;
            #pragma unroll
            for (int q = 0; q < 16; q++)
                *(uint4*)(SO + q * 4096 + t * 16) =
                    *(const uint4*)(qt8 + q * 4096 + t * 16);
            if (lane < 16) {
                #pragma unroll
                for (int cb = 0; cb < 2; cb++) {
                    int rsl = w * 32 + cb * 16 + lane;
                    *(float*)(SO + 65536 + rsl * 4) = rs[cb];
                }
            }
        } else {
            // ---- C -> next B (bf8) via 4-round intra-wave exchange ---------
            // scr row r (0..15) holds col (cb*16+r)'s j-bytes for this kf2,
            // 16B blocks XOR-swizzled by (row&7).
            #pragma unroll
            for (int kf2 = 0; kf2 < 2; kf2++) {
                #pragma unroll
                for (int cb = 0; cb < 2; cb++) {
                    #pragma unroll
                    for (int jbl = 0; jbl < 8; jbl++) {
                        const int jb = kf2 * 8 + jbl;
                        unsigned pk = pk4bf8(Cacc[jb][cb][0] * rn[cb],
                                             Cacc[jb][cb][1] * rn[cb],
                                             Cacc[jb][cb][2] * rn[cb],
                                             Cacc[jb][cb][3] * rn[cb]);
                        const int addr = ln15 * 128 + (((jbl * 16) ^ swz) + gl * 4);
                        *(unsigned*)(mysc + addr) = pk;
                    }
                    asm volatile("s_waitcnt lgkmcnt(0)" ::: "memory");
                    __builtin_amdgcn_sched_barrier(0);
                    uint4 r0 = *(const uint4*)(mysc + ln15 * 128 + ((gl * 32) ^ swz));
                    uint4 r1 = *(const uint4*)(mysc + ln15 * 128 + ((gl * 32 + 16) ^ swz));
                    U256 b;
                    b.u[0] = r0.x; b.u[1] = r0.y; b.u[2] = r0.z; b.u[3] = r0.w;
                    b.u[4] = r1.x; b.u[5] = r1.y; b.u[6] = r1.z; b.u[7] = r1.w;
                    Bf[kf2][cb] = b.v;
                    asm volatile("s_waitcnt lgkmcnt(0)" ::: "memory");
                    __builtin_amdgcn_sched_barrier(0);
                }
            }
            eld[(i + 1) & 1][t] = __expf(enext);
            __syncthreads();
        }
    }
}

// ===========================================================================
// Binary-combine body (round-9, proven): out (p,h) = Later(2p+1) x
// Earlier(2p), columns [128h,128h+128), linear storage.
// ===========================================================================
__device__ __forceinline__ void combine_body(
        const char* __restrict__ inb, char* __restrict__ outb,
        int p, int h, char* qt, unsigned (*scr)[512],
        float* efac, float* smax,
        int t, int lane, int w, int gl, int ln15) {
    const char* SL0 = inb + (size_t)(4 * p + 2) * SLOT2;
    const char* SL1 = inb + (size_t)(4 * p + 3) * SLOT2;
    const char* SE  = inb + (size_t)(4 * p + h) * SLOT2;
    char* SO = outb + (size_t)(2 * p + h) * SLOT2;

    float sv = *(const float*)(((t < 128) ? SL0 : SL1) + 65536 + (t & 127) * 4);
    float m = sv;
    #pragma unroll
    for (int off = 32; off; off >>= 1) m = fmaxf(m, __shfl_xor(m, off));
    if (lane == 0) smax[w] = m;
    __syncthreads();
    const float sigma = fmaxf(fmaxf(smax[0], smax[1]), fmaxf(smax[2], smax[3]));
    efac[t] = __expf(sv - sigma);
    __syncthreads();

    for (int it = 0; it < 32; it++) {
        int off = it * 2048 + t * 8;
        int j = off >> 8, k = off & 255;
        const char* src = (k < 128) ? (SL0 + (size_t)(j * 128 + k) * 2)
                                    : (SL1 + (size_t)(j * 128 + (k - 128)) * 2);
        uint4 d = *(const uint4*)src;
        float4 e0 = *(const float4*)&efac[k];
        float4 e1 = *(const float4*)&efac[k + 4];
        float ef[8] = {e0.x, e0.y, e0.z, e0.w, e1.x, e1.y, e1.z, e1.w};
        unsigned wds[4] = {d.x, d.y, d.z, d.w};
        unsigned outw[4];
        #pragma unroll
        for (int wi = 0; wi < 4; wi++) {
            float lo = bf2f((unsigned short)(wds[wi] & 0xffffu)) * ef[2 * wi];
            float hi = bf2f((unsigned short)(wds[wi] >> 16)) * ef[2 * wi + 1];
            outw[wi] = pk2(lo, hi);
        }
        uint4 o; o.x = outw[0]; o.y = outw[1]; o.z = outw[2]; o.w = outw[3];
        *(uint4*)(qt + ((j * 512 + k * 2) ^ ((j & 7) << 4))) = o;
    }

    bf16x8 Bf[8][2];
    #pragma unroll
    for (int kf = 0; kf < 8; kf++) {
        #pragma unroll
        for (int p2 = 0; p2 < 2; p2++) {
            int kk = p2 * 16 + (lane >> 2);
            uint4 d = *(const uint4*)(SE + (size_t)(32 * kf + kk) * 256
                                      + w * 64 + (lane & 3) * 16);
            *(uint4*)((char*)&scr[w][0] + kk * 64 + (lane & 3) * 16) = d;
        }
        asm volatile("s_waitcnt lgkmcnt(0)" ::: "memory");
        __builtin_amdgcn_sched_barrier(0);
        #pragma unroll
        for (int cb = 0; cb < 2; cb++) {
            unsigned wd[4] = {0u, 0u, 0u, 0u};
            #pragma unroll
            for (int e = 0; e < 8; e++) {
                int kloc = gl * 8 + e;
                unsigned short hh = *(const unsigned short*)
                    ((const char*)&scr[w][0] + kloc * 64 + (cb * 16 + ln15) * 2);
                wd[e >> 1] |= ((unsigned)hh) << (16 * (e & 1));
            }
            U128 q; q.u.x = wd[0]; q.u.y = wd[1]; q.u.z = wd[2]; q.u.w = wd[3];
            Bf[kf][cb] = q.v;
        }
        asm volatile("s_waitcnt lgkmcnt(0)" ::: "memory");
        __builtin_amdgcn_sched_barrier(0);
    }
    __syncthreads();

    f32x4 Cacc[16][2];
    #pragma unroll
    for (int jb = 0; jb < 16; jb++)
        #pragma unroll
        for (int cb = 0; cb < 2; cb++) Cacc[jb][cb] = f32x4{0.f, 0.f, 0.f, 0.f};
    const int aswz = (lane & 7) << 4;
    #pragma unroll
    for (int jb = 0; jb < 16; jb++) {
        const int abase = (jb * 16 + ln15) * 512 + gl * 16;
        #pragma unroll
        for (int kf = 0; kf < 8; kf++) {
            U128 a; a.u = *(const uint4*)(qt + ((abase + kf * 64) ^ aswz));
            #pragma unroll
            for (int cb = 0; cb < 2; cb++)
                Cacc[jb][cb] = __builtin_amdgcn_mfma_f32_16x16x32_bf16(
                    a.v, Bf[kf][cb], Cacc[jb][cb], 0, 0, 0);
        }
    }

    float mx[2], rn[2];
    #pragma unroll
    for (int cb = 0; cb < 2; cb++) {
        float m0 = Cacc[0][cb][0];
        #pragma unroll
        for (int jb = 0; jb < 16; jb++)
            #pragma unroll
            for (int rg = 0; rg < 4; rg++) m0 = fmaxf(m0, Cacc[jb][cb][rg]);
        m0 = fmaxf(m0, __shfl_xor(m0, 16));
        m0 = fmaxf(m0, __shfl_xor(m0, 32));
        mx[cb] = m0; rn[cb] = 1.0f / m0;
    }

    __syncthreads();
    #pragma unroll
    for (int jb = 0; jb < 16; jb++)
        #pragma unroll
        for (int cb = 0; cb < 2; cb++) {
            int rsl = w * 32 + cb * 16 + ln15;
            #pragma unroll
            for (int rg = 0; rg < 4; rg++) {
                int j = jb * 16 + gl * 4 + rg;
                *(unsigned short*)(qt + ((j * 128 + rsl) << 1)) =
                    (unsigned short)f2bfu(Cacc[jb][cb][rg] * rn[cb]);
            }
        }
    __syncthreads();
    #pragma unroll
    for (int q = 0; q < 16; q++)
        *(uint4*)(SO + q * 4096 + t * 16) = *(const uint4*)(qt + q * 4096 + t * 16);
    if (lane < 16) {
        #pragma unroll
        for (int cb = 0; cb < 2; cb++) {
            int rsl = w * 32 + cb * 16 + lane;
            float se = *(const float*)(SE + 65536 + rsl * 4);
            *(float*)(SO + 65536 + rsl * 4) = se + sigma + __logf(mx[cb]);
        }
    }
}

__global__ __launch_bounds__(256, 1) void crf_combine2(
        const char* __restrict__ inb, char* __restrict__ outb) {
    __shared__ alignas(16) char qt[131072];
    __shared__ alignas(16) unsigned scr[4][512];
    __shared__ alignas(16) float efac[NTS];
    __shared__ float smax[4];
    const int t = threadIdx.x;
    combine_body(inb, outb, blockIdx.x >> 1, blockIdx.x & 1, qt, scr, efac, smax,
                 t, t & 63, t >> 6, (t & 63) >> 4, t & 15);
}

// ===========================================================================
// Fused chain + finalize + gold (round-9/15, proven): 16 serial matvecs.
// ===========================================================================
__global__ __launch_bounds__(512) void crf_chainfin16(
        const char* __restrict__ mats, const float* __restrict__ emit,
        const float* __restrict__ BOS, const int* __restrict__ y,
        const float* __restrict__ trans, const float* __restrict__ EOS,
        float* __restrict__ out) {
    __shared__ float red[8];
    __shared__ float smx[8];
    __shared__ alignas(16) float u[NTS];
    __shared__ float pu[NTS];
    const int t = threadIdx.x, lane = t & 63, wv = t >> 6;

    float s = 0.f;
    for (int i = t; i < TLEN - 1; i += 512) {
        int yi = y[i], yn = y[i + 1];
        s += trans[yi * NTS + yn] + emit[i * NTS + yi];
    }
    #pragma unroll
    for (int off = 32; off; off >>= 1) s += __shfl_down(s, off);
    if (lane == 0) red[wv] = s;

    float v0 = (t < NTS) ? (BOS[t] + emit[t]) : -INFINITY;
    float m = v0;
    #pragma unroll
    for (int off = 32; off; off >>= 1) m = fmaxf(m, __shfl_xor(m, off));
    if (lane == 0) smx[wv] = m;
    __syncthreads();
    const float m0 = fmaxf(fmaxf(smx[0], smx[1]), fmaxf(smx[2], smx[3]));
    float wreg = (t < NTS) ? __expf(v0 - m0) : 0.f;
    double W = (double)m0;
    __syncthreads();

    const int j2 = t & 255;
    const int hh = t >> 8;
    for (int c = 0; c < 16; ++c) {
        const char* M0 = mats + (size_t)(2 * c) * SLOT2;
        const char* M1 = M0 + SLOT2;

        const char* Mh = hh ? M1 : M0;
        const uint4* rowp = (const uint4*)(Mh + (size_t)j2 * 256);
        uint4 regs[16];
        #pragma unroll
        for (int q = 0; q < 16; q++) regs[q] = rowp[q];

        float sv = -INFINITY;
        if (t < NTS) sv = *(const float*)(((t < 128) ? M0 : M1) + 65536 + (t & 127) * 4);
        m = sv;
        #pragma unroll
        for (int off = 32; off; off >>= 1) m = fmaxf(m, __shfl_xor(m, off));
        if (lane == 0) smx[wv] = m;
        __syncthreads();
        const float sigma = fmaxf(fmaxf(smx[0], smx[1]), fmaxf(smx[2], smx[3]));
        if (t < NTS) u[t] = __expf(sv - sigma) * wreg;
        __syncthreads();

        const float* ub = u + hh * 128;
        float acc = 0.f;
        #pragma unroll
        for (int q = 0; q < 16; q++) acc += dot8(regs[q], ub + q * 8);
        if (hh == 1) pu[j2] = acc;
        __syncthreads();
        float v = -INFINITY;
        if (t < NTS) v = acc + pu[t];
        m = v;
        #pragma unroll
        for (int off = 32; off; off >>= 1) m = fmaxf(m, __shfl_xor(m, off));
        if (lane == 0) smx[wv] = m;
        __syncthreads();
        const float mstep = fmaxf(fmaxf(smx[0], smx[1]), fmaxf(smx[2], smx[3]));
        W += (double)(sigma + __logf(mstep));
        if (t < NTS) wreg = v * (1.0f / mstep);
        __syncthreads();
    }

    float ssum = (t < NTS) ? wreg : 0.f;
    #pragma unroll
    for (int off = 32; off; off >>= 1) ssum += __shfl_down(ssum, off);
    if (lane == 0) smx[wv] = ssum;
    __syncthreads();
    if (t == 0) {
        float S = smx[0] + smx[1] + smx[2] + smx[3];
        float logZ = (float)(W + (double)__logf(S));
        float gold = 0.f;
        #pragma unroll
        for (int k = 0; k < 8; k++) gold += red[k];
        int y0 = y[0], yl = y[TLEN - 1];
        gold += BOS[y0] + EOS[yl] + emit[(TLEN - 1) * NTS + yl];
        out[0] = logZ - gold;
    }
}

// ===========================================================================
// Serial fallback (ws too small) — unchanged, verified
// ===========================================================================
__global__ __launch_bounds__(256) void crf_prep(const float* __restrict__ trans,
                                                __half2* __restrict__ Qp) {
    int j = threadIdx.x, p = blockIdx.x;
    float a = __expf(trans[(2 * p) * NTS + j]);
    float b = __expf(trans[(2 * p + 1) * NTS + j]);
    Qp[p * NTS + j] = __floats2half2_rn(a, b);
}

__global__ __launch_bounds__(512) void crf_forward(
        const float* __restrict__ emit, const float* __restrict__ BOS,
        const __half2* __restrict__ Qp_g, float* __restrict__ logZ_out) {
    __shared__ __half2 Qp[128 * NTS];
    __shared__ alignas(16) float w[NTS];
    __shared__ float part[2][NTS];
    __shared__ float ebuf[2][NTS];
    __shared__ float wavemax[8];
    const int t = threadIdx.x, j = t & 255, q = t >> 8, lane = t & 63, wv = t >> 6;
    for (int idx = t; idx < 128 * NTS; idx += 512) Qp[idx] = Qp_g[idx];
    float anew = -INFINITY;
    if (t < NTS) anew = BOS[t] + emit[t];
    float ml = anew;
    #pragma unroll
    for (int off = 32; off; off >>= 1) ml = fmaxf(ml, __shfl_down(ml, off));
    if (lane == 0) wavemax[wv] = ml;
    __syncthreads();
    float mstep = fmaxf(fmaxf(wavemax[0], wavemax[1]), fmaxf(wavemax[2], wavemax[3]));
    double Macc = (double)mstep;
    if (t < NTS) w[t] = __expf(anew - mstep);
    float epre = 0.f;
    if (q == 1) epre = emit[NTS + j];
    __syncthreads();
    for (int i = 1; i < TLEN; ++i) {
        if (q == 1) ebuf[i & 1][j] = epre;
        float acc = 0.f;
        const __half2* qptr = Qp + (q * 64) * NTS + j;
        const float2* wptr = (const float2*)(w + q * 128);
        #pragma unroll 16
        for (int kk = 0; kk < 64; ++kk) {
            __half2 qv = qptr[kk * NTS];
            float2 wv2 = wptr[kk];
            acc += __low2float(qv) * wv2.x + __high2float(qv) * wv2.y;
        }
        part[q][j] = acc;
        if (q == 1 && (i + 1) < TLEN) epre = emit[(i + 1) * NTS + j];
        __syncthreads();
        float an = 0.f;
        ml = -INFINITY;
        if (t < NTS) {
            float vv = part[0][t] + part[1][t];
            an = ebuf[i & 1][t] + __logf(vv);
            ml = an;
        }
        #pragma unroll
        for (int off = 32; off; off >>= 1) ml = fmaxf(ml, __shfl_down(ml, off));
        if (lane == 0 && wv < 4) wavemax[wv] = ml;
        __syncthreads();
        mstep = fmaxf(fmaxf(wavemax[0], wavemax[1]), fmaxf(wavemax[2], wavemax[3]));
        Macc += (double)mstep;
        if (t < NTS) w[t] = __expf(an - mstep);
        __syncthreads();
    }
    float s = (t < NTS) ? w[t] : 0.f;
    #pragma unroll
    for (int off = 32; off; off >>= 1) s += __shfl_down(s, off);
    if (lane == 0 && wv < 4) wavemax[wv] = s;
    __syncthreads();
    if (t == 0) {
        float tot = wavemax[0] + wavemax[1] + wavemax[2] + wavemax[3];
        logZ_out[0] = (float)(Macc + (double)__logf(tot));
    }
}

__global__ __launch_bounds__(512) void crf_gold(
        const float* __restrict__ emit, const int* __restrict__ y,
        const float* __restrict__ trans, const float* __restrict__ BOS,
        const float* __restrict__ EOS, const float* __restrict__ logZ_ws,
        float* __restrict__ out) {
    __shared__ float red[8];
    int t = threadIdx.x;
    float s = 0.f;
    for (int i = t; i < TLEN - 1; i += 512) {
        int yi = y[i], yn = y[i + 1];
        s += trans[yi * NTS + yn] + emit[i * NTS + yi];
    }
    #pragma unroll
    for (int off = 32; off; off >>= 1) s += __shfl_down(s, off);
    if ((t & 63) == 0) red[t >> 6] = s;
    __syncthreads();
    if (t == 0) {
        float tot = 0.f;
        #pragma unroll
        for (int k2 = 0; k2 < 8; ++k2) tot += red[k2];
        int y0 = y[0], yl = y[TLEN - 1];
        tot += BOS[y0] + EOS[yl] + emit[(TLEN - 1) * NTS + yl];
        out[0] = logZ_ws[0] - tot;
    }
}

// ===========================================================================
extern "C" void kernel_launch(void* const* d_in, const int* in_sizes, int n_in,
                              void* d_out, int out_size, void* d_ws, size_t ws_size,
                              hipStream_t stream) {
    const float* emit  = (const float*)d_in[0];
    const int*   y     = (const int*)d_in[1];
    const float* trans = (const float*)d_in[2];
    const float* BOS   = (const float*)d_in[3];
    const float* EOS   = (const float*)d_in[4];
    float* out = (float*)d_out;

    const size_t need = (size_t)(512 + 256) * SLOT2 + 256;
    if (ws_size >= need) {
        char* X = (char*)d_ws;                       // 512 half-slots
        char* Y = X + (size_t)512 * SLOT2;           // 256 half-slots

        crf_phase1<<<2 * NCH, 256, 0, stream>>>(emit, trans, X);
        crf_combine2<<<256, 256, 0, stream>>>(X, Y);   // 256 -> 128 matrices
        crf_combine2<<<128, 256, 0, stream>>>(Y, X);   // 128 -> 64
        crf_combine2<<<64, 256, 0, stream>>>(X, Y);    //  64 -> 32
        crf_combine2<<<32, 256, 0, stream>>>(Y, X);    //  32 -> 16
        crf_chainfin16<<<1, 512, 0, stream>>>(X, emit, BOS, y, trans, EOS, out);
    } else {
        __half2* Qp = (__half2*)d_ws;
        float* logZ = (float*)((char*)d_ws + 128 * NTS * sizeof(__half2));
        crf_prep<<<128, 256, 0, stream>>>(trans, Qp);
        crf_forward<<<1, 512, 0, stream>>>(emit, BOS, Qp, logZ);
        crf_gold<<<1, 512, 0, stream>>>(emit, y, trans, BOS, EOS, logZ, out);
    }
}

// Round 17
// 369.399 us; speedup vs baseline: 1.4891x; 1.0667x over previous
//
#include <hip/hip_runtime.h>
#include <hip/hip_fp16.h>

#define TLEN 8192
#define NTS  256
#define CLEN 32
#define NCH  256           // TLEN / CLEN
#define SLOT2 66048        // 256*128 bf16 (65536) + 128 f32 scales (512)

typedef __bf16 bf16x8 __attribute__((ext_vector_type(8)));
typedef float  f32x4  __attribute__((ext_vector_type(4)));
typedef int    v8i    __attribute__((ext_vector_type(8)));
union U128 { uint4 u; bf16x8 v; };
union U64  { uint2 u; long l; };
union U256 { unsigned u[8]; v8i v; };

__device__ __forceinline__ unsigned f2bfu(float x) {
    unsigned u = __float_as_uint(x);
    return (u + 0x7fffu + ((u >> 16) & 1u)) >> 16;
}
__device__ __forceinline__ unsigned pk2(float lo, float hi) {
    return f2bfu(lo) | (f2bfu(hi) << 16);
}
__device__ __forceinline__ float bf2f(unsigned short h) {
    return __uint_as_float(((unsigned)h) << 16);
}
__device__ __forceinline__ unsigned pk4bf8(float a, float b, float c, float d) {
    int r = __builtin_amdgcn_cvt_pk_bf8_f32(a, b, 0, false);
    r = __builtin_amdgcn_cvt_pk_bf8_f32(c, d, r, true);
    return (unsigned)r;
}
__device__ __forceinline__ float dot8(uint4 a, const float* uq) {
    return bf2f((unsigned short)(a.x & 0xffffu)) * uq[0]
         + bf2f((unsigned short)(a.x >> 16))     * uq[1]
         + bf2f((unsigned short)(a.y & 0xffffu)) * uq[2]
         + bf2f((unsigned short)(a.y >> 16))     * uq[3]
         + bf2f((unsigned short)(a.z & 0xffffu)) * uq[4]
         + bf2f((unsigned short)(a.z >> 16))     * uq[5]
         + bf2f((unsigned short)(a.w & 0xffffu)) * uq[6]
         + bf2f((unsigned short)(a.w >> 16))     * uq[7];
}

// ===========================================================================
// Phase 1 (MX-fp8 K=128): round-16 structure, but qt8 layout holds each
// lane's 32-B A-operand CONTIGUOUS (8 rotated 32-B granule-blocks per row)
// -> A loads as 2x ds_read_b128 straight into the v8i tuple (no assembly
// movs, half the LDS read instructions).
// ===========================================================================
__global__ __launch_bounds__(256, 2) void crf_phase1(
        const float* __restrict__ emit, const float* __restrict__ trans,
        char* __restrict__ outX) {
    __shared__ alignas(16) char qt8[65536];      // QT[j][k] bf8, block-rotated
    __shared__ alignas(16) char scr[4][2048];    // exchange: 16 rows x 128 B/wave
    __shared__ alignas(16) float eld[2][NTS];    // exp(emit row), dbuf

    const int t    = threadIdx.x;
    const int lane = t & 63;
    const int w    = t >> 6;              // 0..3
    const int gl   = lane >> 4;           // 0..3
    const int ln15 = lane & 15;
    const int c    = blockIdx.x >> 1;
    const int h    = blockIdx.x & 1;
    const int istart = (c == 0) ? 1 : CLEN * c;
    const int iend   = CLEN * c + CLEN;

    // ---- stage QT[j][k] = exp(trans[k][j]) as bf8, rotated 32B blocks ----
    {
        const int r7 = t & 7;
        for (int gk = 0; gk < 32; gk++) {
            float v[8];
            #pragma unroll
            for (int e = 0; e < 8; e++) v[e] = __expf(trans[(gk * 8 + e) * NTS + t]);
            uint2 u;
            u.x = pk4bf8(v[0], v[1], v[2], v[3]);
            u.y = pk4bf8(v[4], v[5], v[6], v[7]);
            const int g4 = gk >> 2, q = gk & 3;
            *(uint2*)(qt8 + t * 256 + (((g4 + r7) & 7) << 5) + q * 8) = u;
        }
    }
    eld[istart & 1][t] = __expf(emit[istart * NTS + t]);

    // ---- A-read block offsets: lane needs block g4 = kf2*4 + gl ----------
    int aoff2[2];
    #pragma unroll
    for (int kf2 = 0; kf2 < 2; kf2++)
        aoff2[kf2] = (((kf2 * 4 + gl) + (ln15 & 7)) & 7) << 5;

    // ---- B := Identity columns (bf8 1.0 = 0x3C), rs := 0 -----------------
    v8i Bf[2][2];
    #pragma unroll
    for (int kf2 = 0; kf2 < 2; kf2++)
        #pragma unroll
        for (int cb = 0; cb < 2; cb++) {
            U256 b;
            #pragma unroll
            for (int q = 0; q < 8; q++) b.u[q] = 0u;
            const int r_glob = 128 * h + 32 * w + cb * 16 + ln15;
            const int e = r_glob - kf2 * 128 - gl * 32;
            if (e >= 0 && e < 32) b.u[e >> 2] = 0x3Cu << (8 * (e & 3));
            Bf[kf2][cb] = b.v;
        }
    float rs[2] = {0.f, 0.f};
    const int swz = (ln15 & 7) << 4;
    __syncthreads();

    char* const mysc = &scr[w][0];
    for (int i = istart; i < iend; ++i) {
        float enext = 0.f;
        if (i + 1 < iend) enext = emit[(i + 1) * NTS + t];

        // ---- C = QT * B (MX bf8 MFMA, K=128, unit scales) -----------------
        f32x4 Cacc[16][2];
        #pragma unroll
        for (int jb = 0; jb < 16; jb++)
            #pragma unroll
            for (int cb = 0; cb < 2; cb++) Cacc[jb][cb] = f32x4{0.f, 0.f, 0.f, 0.f};

        #pragma unroll
        for (int jb = 0; jb < 16; jb++) {
            const char* rowb = qt8 + (jb * 16 + ln15) * 256;
            #pragma unroll
            for (int kf2 = 0; kf2 < 2; kf2++) {
                uint4 lo = *(const uint4*)(rowb + aoff2[kf2]);
                uint4 hi = *(const uint4*)(rowb + aoff2[kf2] + 16);
                U256 a;
                a.u[0] = lo.x; a.u[1] = lo.y; a.u[2] = lo.z; a.u[3] = lo.w;
                a.u[4] = hi.x; a.u[5] = hi.y; a.u[6] = hi.z; a.u[7] = hi.w;
                #pragma unroll
                for (int cb = 0; cb < 2; cb++)
                    Cacc[jb][cb] = __builtin_amdgcn_mfma_scale_f32_16x16x128_f8f6f4(
                        a.v, Bf[kf2][cb], Cacc[jb][cb],
                        1, 1,            // cbsz=bf8(e5m2), blgp=bf8(e5m2)
                        0, 0x7F,         // opsel_a, scale_a (e8m0 127 = x1)
                        0, 0x7F);        // opsel_b, scale_b
            }
        }

        // ---- scale rows j by exp(emit[i][j]) ------------------------------
        #pragma unroll
        for (int jb = 0; jb < 16; jb++) {
            float4 ev = *(const float4*)&eld[i & 1][jb * 16 + gl * 4];
            #pragma unroll
            for (int cb = 0; cb < 2; cb++) {
                Cacc[jb][cb][0] *= ev.x; Cacc[jb][cb][1] *= ev.y;
                Cacc[jb][cb][2] *= ev.z; Cacc[jb][cb][3] *= ev.w;
            }
        }
        // ---- per-column max + renormalize ---------------------------------
        float rn[2];
        #pragma unroll
        for (int cb = 0; cb < 2; cb++) {
            float m0 = Cacc[0][cb][0];
            #pragma unroll
            for (int jb = 0; jb < 16; jb++)
                #pragma unroll
                for (int rg = 0; rg < 4; rg++) m0 = fmaxf(m0, Cacc[jb][cb][rg]);
            m0 = fmaxf(m0, __shfl_xor(m0, 16));
            m0 = fmaxf(m0, __shfl_xor(m0, 32));
            rn[cb] = 1.0f / m0;
            rs[cb] += __logf(m0);
        }

        if (i == iend - 1) {
            // ---- coalesced write: scatter into qt8 (dead), then copy out ---
            __syncthreads();              // all waves done reading qt8 (MFMA)
            #pragma unroll
            for (int jb = 0; jb < 16; jb++)
                #pragma unroll
                for (int cb = 0; cb < 2; cb++) {
                    int rsl = w * 32 + cb * 16 + ln15;
                    #pragma unroll
                    for (int rg = 0; rg < 4; rg++) {
                        int j = jb * 16 + gl * 4 + rg;
                        *(unsigned short*)(qt8 + ((j * 128 + rsl) << 1)) =
                            (unsigned short)f2bfu(Cacc[jb][cb][rg] * rn[cb]);
                    }
                }
            __syncthreads();
            char* SO = outX + (size_t)(2 * c + h) * SLOT2;
            #pragma unroll
            for (int q = 0; q < 16; q++)
                *(uint4*)(SO + q * 4096 + t * 16) =
                    *(const uint4*)(qt8 + q * 4096 + t * 16);
            if (lane < 16) {
                #pragma unroll
                for (int cb = 0; cb < 2; cb++) {
                    int rsl = w * 32 + cb * 16 + lane;
                    *(float*)(SO + 65536 + rsl * 4) = rs[cb];
                }
            }
        } else {
            // ---- C -> next B (bf8) via 4-round intra-wave exchange ---------
            #pragma unroll
            for (int kf2 = 0; kf2 < 2; kf2++) {
                #pragma unroll
                for (int cb = 0; cb < 2; cb++) {
                    #pragma unroll
                    for (int jbl = 0; jbl < 8; jbl++) {
                        const int jb = kf2 * 8 + jbl;
                        unsigned pk = pk4bf8(Cacc[jb][cb][0] * rn[cb],
                                             Cacc[jb][cb][1] * rn[cb],
                                             Cacc[jb][cb][2] * rn[cb],
                                             Cacc[jb][cb][3] * rn[cb]);
                        const int addr = ln15 * 128 + (((jbl * 16) ^ swz) + gl * 4);
                        *(unsigned*)(mysc + addr) = pk;
                    }
                    asm volatile("s_waitcnt lgkmcnt(0)" ::: "memory");
                    __builtin_amdgcn_sched_barrier(0);
                    uint4 r0 = *(const uint4*)(mysc + ln15 * 128 + ((gl * 32) ^ swz));
                    uint4 r1 = *(const uint4*)(mysc + ln15 * 128 + ((gl * 32 + 16) ^ swz));
                    U256 b;
                    b.u[0] = r0.x; b.u[1] = r0.y; b.u[2] = r0.z; b.u[3] = r0.w;
                    b.u[4] = r1.x; b.u[5] = r1.y; b.u[6] = r1.z; b.u[7] = r1.w;
                    Bf[kf2][cb] = b.v;
                    asm volatile("s_waitcnt lgkmcnt(0)" ::: "memory");
                    __builtin_amdgcn_sched_barrier(0);
                }
            }
            eld[(i + 1) & 1][t] = __expf(enext);
            __syncthreads();
        }
    }
}

// ===========================================================================
// Binary-combine body (round-9, proven): out (p,h) = Later(2p+1) x
// Earlier(2p), columns [128h,128h+128), linear storage.
// ===========================================================================
__device__ __forceinline__ void combine_body(
        const char* __restrict__ inb, char* __restrict__ outb,
        int p, int h, char* qt, unsigned (*scr)[512],
        float* efac, float* smax,
        int t, int lane, int w, int gl, int ln15) {
    const char* SL0 = inb + (size_t)(4 * p + 2) * SLOT2;
    const char* SL1 = inb + (size_t)(4 * p + 3) * SLOT2;
    const char* SE  = inb + (size_t)(4 * p + h) * SLOT2;
    char* SO = outb + (size_t)(2 * p + h) * SLOT2;

    float sv = *(const float*)(((t < 128) ? SL0 : SL1) + 65536 + (t & 127) * 4);
    float m = sv;
    #pragma unroll
    for (int off = 32; off; off >>= 1) m = fmaxf(m, __shfl_xor(m, off));
    if (lane == 0) smax[w] = m;
    __syncthreads();
    const float sigma = fmaxf(fmaxf(smax[0], smax[1]), fmaxf(smax[2], smax[3]));
    efac[t] = __expf(sv - sigma);
    __syncthreads();

    for (int it = 0; it < 32; it++) {
        int off = it * 2048 + t * 8;
        int j = off >> 8, k = off & 255;
        const char* src = (k < 128) ? (SL0 + (size_t)(j * 128 + k) * 2)
                                    : (SL1 + (size_t)(j * 128 + (k - 128)) * 2);
        uint4 d = *(const uint4*)src;
        float4 e0 = *(const float4*)&efac[k];
        float4 e1 = *(const float4*)&efac[k + 4];
        float ef[8] = {e0.x, e0.y, e0.z, e0.w, e1.x, e1.y, e1.z, e1.w};
        unsigned wds[4] = {d.x, d.y, d.z, d.w};
        unsigned outw[4];
        #pragma unroll
        for (int wi = 0; wi < 4; wi++) {
            float lo = bf2f((unsigned short)(wds[wi] & 0xffffu)) * ef[2 * wi];
            float hi = bf2f((unsigned short)(wds[wi] >> 16)) * ef[2 * wi + 1];
            outw[wi] = pk2(lo, hi);
        }
        uint4 o; o.x = outw[0]; o.y = outw[1]; o.z = outw[2]; o.w = outw[3];
        *(uint4*)(qt + ((j * 512 + k * 2) ^ ((j & 7) << 4))) = o;
    }

    bf16x8 Bf[8][2];
    #pragma unroll
    for (int kf = 0; kf < 8; kf++) {
        #pragma unroll
        for (int p2 = 0; p2 < 2; p2++) {
            int kk = p2 * 16 + (lane >> 2);
            uint4 d = *(const uint4*)(SE + (size_t)(32 * kf + kk) * 256
                                      + w * 64 + (lane & 3) * 16);
            *(uint4*)((char*)&scr[w][0] + kk * 64 + (lane & 3) * 16) = d;
        }
        asm volatile("s_waitcnt lgkmcnt(0)" ::: "memory");
        __builtin_amdgcn_sched_barrier(0);
        #pragma unroll
        for (int cb = 0; cb < 2; cb++) {
            unsigned wd[4] = {0u, 0u, 0u, 0u};
            #pragma unroll
            for (int e = 0; e < 8; e++) {
                int kloc = gl * 8 + e;
                unsigned short hh = *(const unsigned short*)
                    ((const char*)&scr[w][0] + kloc * 64 + (cb * 16 + ln15) * 2);
                wd[e >> 1] |= ((unsigned)hh) << (16 * (e & 1));
            }
            U128 q; q.u.x = wd[0]; q.u.y = wd[1]; q.u.z = wd[2]; q.u.w = wd[3];
            Bf[kf][cb] = q.v;
        }
        asm volatile("s_waitcnt lgkmcnt(0)" ::: "memory");
        __builtin_amdgcn_sched_barrier(0);
    }
    __syncthreads();

    f32x4 Cacc[16][2];
    #pragma unroll
    for (int jb = 0; jb < 16; jb++)
        #pragma unroll
        for (int cb = 0; cb < 2; cb++) Cacc[jb][cb] = f32x4{0.f, 0.f, 0.f, 0.f};
    const int aswz = (lane & 7) << 4;
    #pragma unroll
    for (int jb = 0; jb < 16; jb++) {
        const int abase = (jb * 16 + ln15) * 512 + gl * 16;
        #pragma unroll
        for (int kf = 0; kf < 8; kf++) {
            U128 a; a.u = *(const uint4*)(qt + ((abase + kf * 64) ^ aswz));
            #pragma unroll
            for (int cb = 0; cb < 2; cb++)
                Cacc[jb][cb] = __builtin_amdgcn_mfma_f32_16x16x32_bf16(
                    a.v, Bf[kf][cb], Cacc[jb][cb], 0, 0, 0);
        }
    }

    float mx[2], rn[2];
    #pragma unroll
    for (int cb = 0; cb < 2; cb++) {
        float m0 = Cacc[0][cb][0];
        #pragma unroll
        for (int jb = 0; jb < 16; jb++)
            #pragma unroll
            for (int rg = 0; rg < 4; rg++) m0 = fmaxf(m0, Cacc[jb][cb][rg]);
        m0 = fmaxf(m0, __shfl_xor(m0, 16));
        m0 = fmaxf(m0, __shfl_xor(m0, 32));
        mx[cb] = m0; rn[cb] = 1.0f / m0;
    }

    __syncthreads();
    #pragma unroll
    for (int jb = 0; jb < 16; jb++)
        #pragma unroll
        for (int cb = 0; cb < 2; cb++) {
            int rsl = w * 32 + cb * 16 + ln15;
            #pragma unroll
            for (int rg = 0; rg < 4; rg++) {
                int j = jb * 16 + gl * 4 + rg;
                *(unsigned short*)(qt + ((j * 128 + rsl) << 1)) =
                    (unsigned short)f2bfu(Cacc[jb][cb][rg] * rn[cb]);
            }
        }
    __syncthreads();
    #pragma unroll
    for (int q = 0; q < 16; q++)
        *(uint4*)(SO + q * 4096 + t * 16) = *(const uint4*)(qt + q * 4096 + t * 16);
    if (lane < 16) {
        #pragma unroll
        for (int cb = 0; cb < 2; cb++) {
            int rsl = w * 32 + cb * 16 + lane;
            float se = *(const float*)(SE + 65536 + rsl * 4);
            *(float*)(SO + 65536 + rsl * 4) = se + sigma + __logf(mx[cb]);
        }
    }
}

__global__ __launch_bounds__(256, 1) void crf_combine2(
        const char* __restrict__ inb, char* __restrict__ outb) {
    __shared__ alignas(16) char qt[131072];
    __shared__ alignas(16) unsigned scr[4][512];
    __shared__ alignas(16) float efac[NTS];
    __shared__ float smax[4];
    const int t = threadIdx.x;
    combine_body(inb, outb, blockIdx.x >> 1, blockIdx.x & 1, qt, scr, efac, smax,
                 t, t & 63, t >> 6, (t & 63) >> 4, t & 15);
}

// ===========================================================================
// Fused chain + finalize + gold (round-9/15, proven): 16 serial matvecs.
// ===========================================================================
__global__ __launch_bounds__(512) void crf_chainfin16(
        const char* __restrict__ mats, const float* __restrict__ emit,
        const float* __restrict__ BOS, const int* __restrict__ y,
        const float* __restrict__ trans, const float* __restrict__ EOS,
        float* __restrict__ out) {
    __shared__ float red[8];
    __shared__ float smx[8];
    __shared__ alignas(16) float u[NTS];
    __shared__ float pu[NTS];
    const int t = threadIdx.x, lane = t & 63, wv = t >> 6;

    float s = 0.f;
    for (int i = t; i < TLEN - 1; i += 512) {
        int yi = y[i], yn = y[i + 1];
        s += trans[yi * NTS + yn] + emit[i * NTS + yi];
    }
    #pragma unroll
    for (int off = 32; off; off >>= 1) s += __shfl_down(s, off);
    if (lane == 0) red[wv] = s;

    float v0 = (t < NTS) ? (BOS[t] + emit[t]) : -INFINITY;
    float m = v0;
    #pragma unroll
    for (int off = 32; off; off >>= 1) m = fmaxf(m, __shfl_xor(m, off));
    if (lane == 0) smx[wv] = m;
    __syncthreads();
    const float m0 = fmaxf(fmaxf(smx[0], smx[1]), fmaxf(smx[2], smx[3]));
    float wreg = (t < NTS) ? __expf(v0 - m0) : 0.f;
    double W = (double)m0;
    __syncthreads();

    const int j2 = t & 255;
    const int hh = t >> 8;
    for (int c = 0; c < 16; ++c) {
        const char* M0 = mats + (size_t)(2 * c) * SLOT2;
        const char* M1 = M0 + SLOT2;

        const char* Mh = hh ? M1 : M0;
        const uint4* rowp = (const uint4*)(Mh + (size_t)j2 * 256);
        uint4 regs[16];
        #pragma unroll
        for (int q = 0; q < 16; q++) regs[q] = rowp[q];

        float sv = -INFINITY;
        if (t < NTS) sv = *(const float*)(((t < 128) ? M0 : M1) + 65536 + (t & 127) * 4);
        m = sv;
        #pragma unroll
        for (int off = 32; off; off >>= 1) m = fmaxf(m, __shfl_xor(m, off));
        if (lane == 0) smx[wv] = m;
        __syncthreads();
        const float sigma = fmaxf(fmaxf(smx[0], smx[1]), fmaxf(smx[2], smx[3]));
        if (t < NTS) u[t] = __expf(sv - sigma) * wreg;
        __syncthreads();

        const float* ub = u + hh * 128;
        float acc = 0.f;
        #pragma unroll
        for (int q = 0; q < 16; q++) acc += dot8(regs[q], ub + q * 8);
        if (hh == 1) pu[j2] = acc;
        __syncthreads();
        float v = -INFINITY;
        if (t < NTS) v = acc + pu[t];
        m = v;
        #pragma unroll
        for (int off = 32; off; off >>= 1) m = fmaxf(m, __shfl_xor(m, off));
        if (lane == 0) smx[wv] = m;
        __syncthreads();
        const float mstep = fmaxf(fmaxf(smx[0], smx[1]), fmaxf(smx[2], smx[3]));
        W += (double)(sigma + __logf(mstep));
        if (t < NTS) wreg = v * (1.0f / mstep);
        __syncthreads();
    }

    float ssum = (t < NTS) ? wreg : 0.f;
    #pragma unroll
    for (int off = 32; off; off >>= 1) ssum += __shfl_down(ssum, off);
    if (lane == 0) smx[wv] = ssum;
    __syncthreads();
    if (t == 0) {
        float S = smx[0] + smx[1] + smx[2] + smx[3];
        float logZ = (float)(W + (double)__logf(S));
        float gold = 0.f;
        #pragma unroll
        for (int k = 0; k < 8; k++) gold += red[k];
        int y0 = y[0], yl = y[TLEN - 1];
        gold += BOS[y0] + EOS[yl] + emit[(TLEN - 1) * NTS + yl];
        out[0] = logZ - gold;
    }
}

// ===========================================================================
// Serial fallback (ws too small) — unchanged, verified
// ===========================================================================
__global__ __launch_bounds__(256) void crf_prep(const float* __restrict__ trans,
                                                __half2* __restrict__ Qp) {
    int j = threadIdx.x, p = blockIdx.x;
    float a = __expf(trans[(2 * p) * NTS + j]);
    float b = __expf(trans[(2 * p + 1) * NTS + j]);
    Qp[p * NTS + j] = __floats2half2_rn(a, b);
}

__global__ __launch_bounds__(512) void crf_forward(
        const float* __restrict__ emit, const float* __restrict__ BOS,
        const __half2* __restrict__ Qp_g, float* __restrict__ logZ_out) {
    __shared__ __half2 Qp[128 * NTS];
    __shared__ alignas(16) float w[NTS];
    __shared__ float part[2][NTS];
    __shared__ float ebuf[2][NTS];
    __shared__ float wavemax[8];
    const int t = threadIdx.x, j = t & 255, q = t >> 8, lane = t & 63, wv = t >> 6;
    for (int idx = t; idx < 128 * NTS; idx += 512) Qp[idx] = Qp_g[idx];
    float anew = -INFINITY;
    if (t < NTS) anew = BOS[t] + emit[t];
    float ml = anew;
    #pragma unroll
    for (int off = 32; off; off >>= 1) ml = fmaxf(ml, __shfl_down(ml, off));
    if (lane == 0) wavemax[wv] = ml;
    __syncthreads();
    float mstep = fmaxf(fmaxf(wavemax[0], wavemax[1]), fmaxf(wavemax[2], wavemax[3]));
    double Macc = (double)mstep;
    if (t < NTS) w[t] = __expf(anew - mstep);
    float epre = 0.f;
    if (q == 1) epre = emit[NTS + j];
    __syncthreads();
    for (int i = 1; i < TLEN; ++i) {
        if (q == 1) ebuf[i & 1][j] = epre;
        float acc = 0.f;
        const __half2* qptr = Qp + (q * 64) * NTS + j;
        const float2* wptr = (const float2*)(w + q * 128);
        #pragma unroll 16
        for (int kk = 0; kk < 64; ++kk) {
            __half2 qv = qptr[kk * NTS];
            float2 wv2 = wptr[kk];
            acc += __low2float(qv) * wv2.x + __high2float(qv) * wv2.y;
        }
        part[q][j] = acc;
        if (q == 1 && (i + 1) < TLEN) epre = emit[(i + 1) * NTS + j];
        __syncthreads();
        float an = 0.f;
        ml = -INFINITY;
        if (t < NTS) {
            float vv = part[0][t] + part[1][t];
            an = ebuf[i & 1][t] + __logf(vv);
            ml = an;
        }
        #pragma unroll
        for (int off = 32; off; off >>= 1) ml = fmaxf(ml, __shfl_down(ml, off));
        if (lane == 0 && wv < 4) wavemax[wv] = ml;
        __syncthreads();
        mstep = fmaxf(fmaxf(wavemax[0], wavemax[1]), fmaxf(wavemax[2], wavemax[3]));
        Macc += (double)mstep;
        if (t < NTS) w[t] = __expf(an - mstep);
        __syncthreads();
    }
    float s = (t < NTS) ? w[t] : 0.f;
    #pragma unroll
    for (int off = 32; off; off >>= 1) s += __shfl_down(s, off);
    if (lane == 0 && wv < 4) wavemax[wv] = s;
    __syncthreads();
    if (t == 0) {
        float tot = wavemax[0] + wavemax[1] + wavemax[2] + wavemax[3];
        logZ_out[0] = (float)(Macc + (double)__logf(tot));
    }
}

__global__ __launch_bounds__(512) void crf_gold(
        const float* __restrict__ emit, const int* __restrict__ y,
        const float* __restrict__ trans, const float* __restrict__ BOS,
        const float* __restrict__ EOS, const float* __restrict__ logZ_ws,
        float* __restrict__ out) {
    __shared__ float red[8];
    int t = threadIdx.x;
    float s = 0.f;
    for (int i = t; i < TLEN - 1; i += 512) {
        int yi = y[i], yn = y[i + 1];
        s += trans[yi * NTS + yn] + emit[i * NTS + yi];
    }
    #pragma unroll
    for (int off = 32; off; off >>= 1) s += __shfl_down(s, off);
    if ((t & 63) == 0) red[t >> 6] = s;
    __syncthreads();
    if (t == 0) {
        float tot = 0.f;
        #pragma unroll
        for (int k2 = 0; k2 < 8; ++k2) tot += red[k2];
        int y0 = y[0], yl = y[TLEN - 1];
        tot += BOS[y0] + EOS[yl] + emit[(TLEN - 1) * NTS + yl];
        out[0] = logZ_ws[0] - tot;
    }
}

// ===========================================================================
extern "C" void kernel_launch(void* const* d_in, const int* in_sizes, int n_in,
                              void* d_out, int out_size, void* d_ws, size_t ws_size,
                              hipStream_t stream) {
    const float* emit  = (const float*)d_in[0];
    const int*   y     = (const int*)d_in[1];
    const float* trans = (const float*)d_in[2];
    const float* BOS   = (const float*)d_in[3];
    const float* EOS   = (const float*)d_in[4];
    float* out = (float*)d_out;

    const size_t need = (size_t)(512 + 256) * SLOT2 + 256;
    if (ws_size >= need) {
        char* X = (char*)d_ws;                       // 512 half-slots
        char* Y = X + (size_t)512 * SLOT2;           // 256 half-slots

        crf_phase1<<<2 * NCH, 256, 0, stream>>>(emit, trans, X);
        crf_combine2<<<256, 256, 0, stream>>>(X, Y);   // 256 -> 128 matrices
        crf_combine2<<<128, 256, 0, stream>>>(Y, X);   // 128 -> 64
        crf_combine2<<<64, 256, 0, stream>>>(X, Y);    //  64 -> 32
        crf_combine2<<<32, 256, 0, stream>>>(Y, X);    //  32 -> 16
        crf_chainfin16<<<1, 512, 0, stream>>>(X, emit, BOS, y, trans, EOS, out);
    } else {
        __half2* Qp = (__half2*)d_ws;
        float* logZ = (float*)((char*)d_ws + 128 * NTS * sizeof(__half2));
        crf_prep<<<128, 256, 0, stream>>>(trans, Qp);
        crf_forward<<<1, 512, 0, stream>>>(emit, BOS, Qp, logZ);
        crf_gold<<<1, 512, 0, stream>>>(emit, y, trans, BOS, EOS, logZ, out);
    }
}